// Round 1
// baseline (2904.592 us; speedup 1.0000x reference)
//
#include <hip/hip_runtime.h>
#include <cstddef>

#define B_     8
#define N_     512
#define HID_   512
#define HEADS_ 16
#define HD_    32
#define FFN_   2048
#define DEMB_  64
#define ROWS   (B_*N_)   // 4096

// ---------------- edge_mask dtype detection ----------------
// numpy bool -> 1 byte/elem (random 0/1 bytes everywhere)
// int32 0/1  -> bytes at offset%4 != 0 are always 0
// flag==1 => byte (bool) layout, flag==0 => int32 layout.
__global__ void detect_mask_kernel(const unsigned char* __restrict__ m,
                                   int* __restrict__ flag) {
  int t = blockIdx.x * blockDim.x + threadIdx.x;  // 65536 threads
  if ((t & 3) != 0) {
    if (m[t] != 0) atomicOr(flag, 1);
  }
}

// ---------------- LayerNorm: one wave per 512-elem row ----------------
__global__ __launch_bounds__(256) void ln_kernel(const float* __restrict__ x,
                                                 const float* __restrict__ g,
                                                 const float* __restrict__ bt,
                                                 float* __restrict__ y) {
  const int lane = threadIdx.x & 63;
  const int row  = blockIdx.x * 4 + (threadIdx.x >> 6);
  const float* xr = x + (size_t)row * HID_;
  float4 v0 = *(const float4*)(xr + lane * 8);
  float4 v1 = *(const float4*)(xr + lane * 8 + 4);
  float s = v0.x + v0.y + v0.z + v0.w + v1.x + v1.y + v1.z + v1.w;
  float q = v0.x*v0.x + v0.y*v0.y + v0.z*v0.z + v0.w*v0.w
          + v1.x*v1.x + v1.y*v1.y + v1.z*v1.z + v1.w*v1.w;
  #pragma unroll
  for (int off = 32; off > 0; off >>= 1) {
    s += __shfl_xor(s, off, 64);
    q += __shfl_xor(q, off, 64);
  }
  const float mean = s * (1.0f / HID_);
  const float var  = q * (1.0f / HID_) - mean * mean;
  const float rs   = rsqrtf(var + 1e-5f);
  const float4 g0 = *(const float4*)(g + lane * 8);
  const float4 g1 = *(const float4*)(g + lane * 8 + 4);
  const float4 b0 = *(const float4*)(bt + lane * 8);
  const float4 b1 = *(const float4*)(bt + lane * 8 + 4);
  float4 o0, o1;
  o0.x = (v0.x - mean) * rs * g0.x + b0.x;
  o0.y = (v0.y - mean) * rs * g0.y + b0.y;
  o0.z = (v0.z - mean) * rs * g0.z + b0.z;
  o0.w = (v0.w - mean) * rs * g0.w + b0.w;
  o1.x = (v1.x - mean) * rs * g1.x + b1.x;
  o1.y = (v1.y - mean) * rs * g1.y + b1.y;
  o1.z = (v1.z - mean) * rs * g1.z + b1.z;
  o1.w = (v1.w - mean) * rs * g1.w + b1.w;
  float* yr = y + (size_t)row * HID_;
  *(float4*)(yr + lane * 8)     = o0;
  *(float4*)(yr + lane * 8 + 4) = o1;
}

// ---------------- fp32 tiled GEMM: C = act(A@W + bias) (+res) ----------------
// A[4096,K] row-major, W[K,N] row-major. BM=BN=64, BK=16, 256 thr, 4x4/thread.
// ACT: 0 none, 1 exact GELU. HAS_RES: C += res (residual add after act).
template <int ACT, bool HAS_RES>
__global__ __launch_bounds__(256) void gemm_kernel(
    const float* __restrict__ A, const float* __restrict__ W,
    const float* __restrict__ bias, const float* __restrict__ res,
    float* __restrict__ C, int N, int K) {
  __shared__ float As[16][68];  // [k][m], pad 68 -> 2-way max on ld/st
  __shared__ float Bs[16][64];  // [k][n]
  const int t  = threadIdx.x;
  const int m0 = blockIdx.y * 64;
  const int n0 = blockIdx.x * 64;
  const int ty = t >> 4, tx = t & 15;          // compute map: rows ty*4.., cols tx*4..
  const int la_k = t & 15, la_m = t >> 4;      // A load map
  const int lb_n = t & 63, lb_k = t >> 6;      // B load map

  float acc[4][4] = {};
  for (int k0 = 0; k0 < K; k0 += 16) {
    #pragma unroll
    for (int r = 0; r < 4; ++r)
      As[la_k][la_m + 16 * r] = A[(size_t)(m0 + la_m + 16 * r) * K + k0 + la_k];
    #pragma unroll
    for (int r = 0; r < 4; ++r)
      Bs[lb_k + 4 * r][lb_n] = W[(size_t)(k0 + lb_k + 4 * r) * N + n0 + lb_n];
    __syncthreads();
    #pragma unroll
    for (int k = 0; k < 16; ++k) {
      const float4 a4 = *(const float4*)&As[k][ty * 4];
      const float4 b4 = *(const float4*)&Bs[k][tx * 4];
      const float av[4] = {a4.x, a4.y, a4.z, a4.w};
      const float bv[4] = {b4.x, b4.y, b4.z, b4.w};
      #pragma unroll
      for (int i = 0; i < 4; ++i)
        #pragma unroll
        for (int j = 0; j < 4; ++j) acc[i][j] += av[i] * bv[j];
    }
    __syncthreads();
  }
  const float4 bb = *(const float4*)(bias + n0 + tx * 4);
  const float bv[4] = {bb.x, bb.y, bb.z, bb.w};
  #pragma unroll
  for (int i = 0; i < 4; ++i) {
    const size_t off = (size_t)(m0 + ty * 4 + i) * N + n0 + tx * 4;
    float v[4];
    #pragma unroll
    for (int j = 0; j < 4; ++j) {
      v[j] = acc[i][j] + bv[j];
      if (ACT == 1) v[j] = 0.5f * v[j] * (1.0f + erff(v[j] * 0.70710678118654752f));
    }
    if (HAS_RES) {
      const float4 rr = *(const float4*)(res + off);
      v[0] += rr.x; v[1] += rr.y; v[2] += rr.z; v[3] += rr.w;
    }
    float4 ov; ov.x = v[0]; ov.y = v[1]; ov.z = v[2]; ov.w = v[3];
    *(float4*)(C + off) = ov;
  }
}

// ---------------- fused distance-bias + mask ----------------
// biasb[b,h,i,j] = mask[b,i,j] ? df[b,i,j,:]@dist_w[:,h] + dist_b[h] : -1e30
// block = (b,i) [4096 blocks], threads over j. Reads df (512MB) exactly once.
__global__ __launch_bounds__(256) void bias_kernel(
    const float* __restrict__ df, const unsigned char* __restrict__ mask8,
    const float* __restrict__ dw, const float* __restrict__ db,
    const int* __restrict__ flag, float* __restrict__ biasb) {
  __shared__ float wT[HEADS_][DEMB_];  // wT[h][d]
  __shared__ float dbs[HEADS_];
  const int t = threadIdx.x;
  for (int idx = t; idx < DEMB_ * HEADS_; idx += 256) {
    wT[idx & 15][idx >> 4] = dw[idx];  // dw[d*16+h]
  }
  if (t < HEADS_) dbs[t] = db[t];
  __syncthreads();
  const int b = blockIdx.x >> 9, i = blockIdx.x & 511;
  const int fb = *flag;
  const int* mask32 = (const int*)mask8;
  for (int j = t; j < N_; j += 256) {
    const float* dfp = df + ((size_t)blockIdx.x * N_ + j) * DEMB_;
    float acc[HEADS_];
    #pragma unroll
    for (int hh = 0; hh < 16; ++hh) acc[hh] = 0.f;
    #pragma unroll
    for (int d4 = 0; d4 < 16; ++d4) {
      const float4 v = *(const float4*)(dfp + d4 * 4);
      #pragma unroll
      for (int hh = 0; hh < 16; ++hh) {
        const float4 w4 = *(const float4*)&wT[hh][d4 * 4];
        acc[hh] += v.x * w4.x + v.y * w4.y + v.z * w4.z + v.w * w4.w;
      }
    }
    const size_t midx = (size_t)blockIdx.x * N_ + j;
    const bool mv = fb ? (mask8[midx] != 0) : (mask32[midx] != 0);
    #pragma unroll
    for (int hh = 0; hh < 16; ++hh) {
      biasb[(((size_t)b * HEADS_ + hh) * N_ + i) * N_ + j] =
          mv ? (acc[hh] + dbs[hh]) : -1e30f;
    }
  }
}

// ---------------- flash attention (fp32, online softmax) ----------------
// block = (b, h, i-half); K/V of one (b,h) staged in LDS (128 KiB).
// One thread per query row i; lockstep over j -> LDS broadcast reads.
__global__ __launch_bounds__(256) void attn_kernel(
    const float* __restrict__ qkv, const float* __restrict__ biasb,
    float* __restrict__ ctx) {
  __shared__ float Ks[N_][HD_];
  __shared__ float Vs[N_][HD_];
  const int t    = threadIdx.x;
  const int b    = blockIdx.x >> 5;
  const int hh   = (blockIdx.x >> 1) & 15;
  const int half = blockIdx.x & 1;
  const size_t qbase = (size_t)b * N_ * (3 * HID_);
  for (int idx = t; idx < N_ * 8; idx += 256) {
    const int j = idx >> 3, f = idx & 7;
    const float* kp = qkv + qbase + (size_t)j * (3 * HID_) + HID_ + hh * HD_ + f * 4;
    *(float4*)&Ks[j][f * 4] = *(const float4*)kp;
    *(float4*)&Vs[j][f * 4] = *(const float4*)(kp + HID_);
  }
  __syncthreads();
  const int i = half * 256 + t;
  const float* qp = qkv + qbase + (size_t)i * (3 * HID_) + hh * HD_;
  float q[HD_];
  #pragma unroll
  for (int f = 0; f < 8; ++f) {
    const float4 v = *(const float4*)(qp + f * 4);
    q[f * 4 + 0] = v.x; q[f * 4 + 1] = v.y; q[f * 4 + 2] = v.z; q[f * 4 + 3] = v.w;
  }
  const float* brow = biasb + (((size_t)b * HEADS_ + hh) * N_ + i) * N_;
  float m = -3.0e38f, l = 0.f;
  float o[HD_];
  #pragma unroll
  for (int d = 0; d < HD_; ++d) o[d] = 0.f;
  for (int j4 = 0; j4 < N_; j4 += 4) {
    const float4 bq = *(const float4*)(brow + j4);
    const float bbv[4] = {bq.x, bq.y, bq.z, bq.w};
    #pragma unroll
    for (int c = 0; c < 4; ++c) {
      const int j = j4 + c;
      float s0 = 0.f, s1 = 0.f, s2 = 0.f, s3 = 0.f;
      #pragma unroll
      for (int d = 0; d < HD_; d += 4) {
        s0 += q[d + 0] * Ks[j][d + 0];
        s1 += q[d + 1] * Ks[j][d + 1];
        s2 += q[d + 2] * Ks[j][d + 2];
        s3 += q[d + 3] * Ks[j][d + 3];
      }
      float s = (s0 + s1) + (s2 + s3);
      s = s * 0.17677669529663687f + bbv[c];  // 1/sqrt(32)
      if (s > m) {
        const float corr = __expf(m - s);
        l *= corr;
        #pragma unroll
        for (int d = 0; d < HD_; ++d) o[d] *= corr;
        m = s;
      }
      const float p = __expf(s - m);
      l += p;
      #pragma unroll
      for (int d = 0; d < HD_; ++d) o[d] += p * Vs[j][d];
    }
  }
  const float inv = 1.0f / l;
  float* cp = ctx + (((size_t)b * N_ + i) * HEADS_ + hh) * HD_;
  #pragma unroll
  for (int f = 0; f < 8; ++f) {
    float4 v;
    v.x = o[f * 4 + 0] * inv; v.y = o[f * 4 + 1] * inv;
    v.z = o[f * 4 + 2] * inv; v.w = o[f * 4 + 3] * inv;
    *(float4*)(cp + f * 4) = v;
  }
}

// ---------------- launcher ----------------
extern "C" void kernel_launch(void* const* d_in, const int* in_sizes, int n_in,
                              void* d_out, int out_size, void* d_ws, size_t ws_size,
                              hipStream_t stream) {
  const float* x      = (const float*)d_in[0];
  const float* df     = (const float*)d_in[1];
  const unsigned char* mask = (const unsigned char*)d_in[2];
  const float* qkv_w  = (const float*)d_in[3];
  const float* qkv_b  = (const float*)d_in[4];
  const float* out_w  = (const float*)d_in[5];
  const float* out_b  = (const float*)d_in[6];
  const float* dist_w = (const float*)d_in[7];
  const float* dist_b = (const float*)d_in[8];
  const float* ln1_g  = (const float*)d_in[9];
  const float* ln1_b  = (const float*)d_in[10];
  const float* ln2_g  = (const float*)d_in[11];
  const float* ln2_b  = (const float*)d_in[12];
  const float* ff1_w  = (const float*)d_in[13];
  const float* ff1_b  = (const float*)d_in[14];
  const float* ff2_w  = (const float*)d_in[15];
  const float* ff2_b  = (const float*)d_in[16];
  float* out = (float*)d_out;

  float* ws    = (float*)d_ws;
  float* h     = ws;                                        // 2,097,152
  float* qkv   = h     + (size_t)ROWS * HID_;               // 6,291,456
  float* biasb = qkv   + (size_t)ROWS * 3 * HID_;           // 33,554,432
  float* ctx   = biasb + (size_t)B_ * HEADS_ * N_ * N_;     // 2,097,152
  float* xa    = ctx   + (size_t)ROWS * HID_;               // 2,097,152
  float* y     = xa    + (size_t)ROWS * HID_;               // 2,097,152
  float* ff1   = y     + (size_t)ROWS * HID_;               // 8,388,608
  int*   flag  = (int*)(ff1 + (size_t)ROWS * FFN_);

  hipMemsetAsync(flag, 0, sizeof(int), stream);
  detect_mask_kernel<<<256, 256, 0, stream>>>(mask, flag);

  // h = LN1(x)
  ln_kernel<<<ROWS / 4, 256, 0, stream>>>(x, ln1_g, ln1_b, h);
  // qkv = h @ qkv_w + qkv_b
  gemm_kernel<0, false><<<dim3(3 * HID_ / 64, ROWS / 64), 256, 0, stream>>>(
      h, qkv_w, qkv_b, nullptr, qkv, 3 * HID_, HID_);
  // biasb = masked distance bias  [B,H,N,N]
  bias_kernel<<<B_ * N_, 256, 0, stream>>>(df, mask, dist_w, dist_b, flag, biasb);
  // ctx = softmax(QK^T/sqrt(hd) + biasb) @ V
  attn_kernel<<<B_ * HEADS_ * 2, 256, 0, stream>>>(qkv, biasb, ctx);
  // xa = x + ctx @ out_w + out_b
  gemm_kernel<0, true><<<dim3(HID_ / 64, ROWS / 64), 256, 0, stream>>>(
      ctx, out_w, out_b, x, xa, HID_, HID_);
  // y = LN2(xa)
  ln_kernel<<<ROWS / 4, 256, 0, stream>>>(xa, ln2_g, ln2_b, y);
  // ff1 = gelu(y @ ff1_w + ff1_b)
  gemm_kernel<1, false><<<dim3(FFN_ / 64, ROWS / 64), 256, 0, stream>>>(
      y, ff1_w, ff1_b, nullptr, ff1, FFN_, HID_);
  // out = xa + ff1 @ ff2_w + ff2_b
  gemm_kernel<0, true><<<dim3(HID_ / 64, ROWS / 64), 256, 0, stream>>>(
      ff1, ff2_w, ff2_b, xa, out, HID_, FFN_);
}

// Round 3
// 850.151 us; speedup vs baseline: 3.4166x; 3.4166x over previous
//
#include <hip/hip_runtime.h>
#include <cstddef>

#define B_     8
#define N_     512
#define HID_   512
#define HEADS_ 16
#define HD_    32
#define FFN_   2048
#define DEMB_  64
#define ROWS   (B_*N_)   // 4096

// ---------------- edge_mask dtype detection ----------------
// numpy bool -> 1 byte/elem (random 0/1 bytes everywhere)
// int32 0/1  -> bytes at offset%4 != 0 are always 0
// flag==1 => byte (bool) layout, flag==0 => int32 layout.
__global__ void detect_mask_kernel(const unsigned char* __restrict__ m,
                                   int* __restrict__ flag) {
  int t = blockIdx.x * blockDim.x + threadIdx.x;  // 65536 threads
  if ((t & 3) != 0) {
    if (m[t] != 0) atomicOr(flag, 1);
  }
}

// ---------------- LayerNorm: one wave per 512-elem row ----------------
__global__ __launch_bounds__(256) void ln_kernel(const float* __restrict__ x,
                                                 const float* __restrict__ g,
                                                 const float* __restrict__ bt,
                                                 float* __restrict__ y) {
  const int lane = threadIdx.x & 63;
  const int row  = blockIdx.x * 4 + (threadIdx.x >> 6);
  const float* xr = x + (size_t)row * HID_;
  float4 v0 = *(const float4*)(xr + lane * 8);
  float4 v1 = *(const float4*)(xr + lane * 8 + 4);
  float s = v0.x + v0.y + v0.z + v0.w + v1.x + v1.y + v1.z + v1.w;
  float q = v0.x*v0.x + v0.y*v0.y + v0.z*v0.z + v0.w*v0.w
          + v1.x*v1.x + v1.y*v1.y + v1.z*v1.z + v1.w*v1.w;
  #pragma unroll
  for (int off = 32; off > 0; off >>= 1) {
    s += __shfl_xor(s, off, 64);
    q += __shfl_xor(q, off, 64);
  }
  const float mean = s * (1.0f / HID_);
  const float var  = q * (1.0f / HID_) - mean * mean;
  const float rs   = rsqrtf(var + 1e-5f);
  const float4 g0 = *(const float4*)(g + lane * 8);
  const float4 g1 = *(const float4*)(g + lane * 8 + 4);
  const float4 b0 = *(const float4*)(bt + lane * 8);
  const float4 b1 = *(const float4*)(bt + lane * 8 + 4);
  float4 o0, o1;
  o0.x = (v0.x - mean) * rs * g0.x + b0.x;
  o0.y = (v0.y - mean) * rs * g0.y + b0.y;
  o0.z = (v0.z - mean) * rs * g0.z + b0.z;
  o0.w = (v0.w - mean) * rs * g0.w + b0.w;
  o1.x = (v1.x - mean) * rs * g1.x + b1.x;
  o1.y = (v1.y - mean) * rs * g1.y + b1.y;
  o1.z = (v1.z - mean) * rs * g1.z + b1.z;
  o1.w = (v1.w - mean) * rs * g1.w + b1.w;
  float* yr = y + (size_t)row * HID_;
  *(float4*)(yr + lane * 8)     = o0;
  *(float4*)(yr + lane * 8 + 4) = o1;
}

// ---------------- fp32 tiled GEMM: C = act(A@W + bias) (+res) ----------------
// A[4096,K] row-major, W[K,N] row-major. BM=BN=64, BK=16, 256 thr, 4x4/thread.
// ACT: 0 none, 1 exact GELU. HAS_RES: C += res (residual add after act).
template <int ACT, bool HAS_RES>
__global__ __launch_bounds__(256) void gemm_kernel(
    const float* __restrict__ A, const float* __restrict__ W,
    const float* __restrict__ bias, const float* __restrict__ res,
    float* __restrict__ C, int N, int K) {
  __shared__ float As[16][68];  // [k][m], pad 68 -> 2-way max on ld/st
  __shared__ float Bs[16][64];  // [k][n]
  const int t  = threadIdx.x;
  const int m0 = blockIdx.y * 64;
  const int n0 = blockIdx.x * 64;
  const int ty = t >> 4, tx = t & 15;          // compute map: rows ty*4.., cols tx*4..
  const int la_k = t & 15, la_m = t >> 4;      // A load map
  const int lb_n = t & 63, lb_k = t >> 6;      // B load map

  float acc[4][4] = {};
  for (int k0 = 0; k0 < K; k0 += 16) {
    #pragma unroll
    for (int r = 0; r < 4; ++r)
      As[la_k][la_m + 16 * r] = A[(size_t)(m0 + la_m + 16 * r) * K + k0 + la_k];
    #pragma unroll
    for (int r = 0; r < 4; ++r)
      Bs[lb_k + 4 * r][lb_n] = W[(size_t)(k0 + lb_k + 4 * r) * N + n0 + lb_n];
    __syncthreads();
    #pragma unroll
    for (int k = 0; k < 16; ++k) {
      const float4 a4 = *(const float4*)&As[k][ty * 4];
      const float4 b4 = *(const float4*)&Bs[k][tx * 4];
      const float av[4] = {a4.x, a4.y, a4.z, a4.w};
      const float bv[4] = {b4.x, b4.y, b4.z, b4.w};
      #pragma unroll
      for (int i = 0; i < 4; ++i)
        #pragma unroll
        for (int j = 0; j < 4; ++j) acc[i][j] += av[i] * bv[j];
    }
    __syncthreads();
  }
  const float4 bb = *(const float4*)(bias + n0 + tx * 4);
  const float bv[4] = {bb.x, bb.y, bb.z, bb.w};
  #pragma unroll
  for (int i = 0; i < 4; ++i) {
    const size_t off = (size_t)(m0 + ty * 4 + i) * N + n0 + tx * 4;
    float v[4];
    #pragma unroll
    for (int j = 0; j < 4; ++j) {
      v[j] = acc[i][j] + bv[j];
      if (ACT == 1) v[j] = 0.5f * v[j] * (1.0f + erff(v[j] * 0.70710678118654752f));
    }
    if (HAS_RES) {
      const float4 rr = *(const float4*)(res + off);
      v[0] += rr.x; v[1] += rr.y; v[2] += rr.z; v[3] += rr.w;
    }
    float4 ov; ov.x = v[0]; ov.y = v[1]; ov.z = v[2]; ov.w = v[3];
    *(float4*)(C + off) = ov;
  }
}

// ---------------- fused distance-bias + mask (v2b: fixed b decode) ----------------
// biasb[b,h,i,j] = mask[b,i,j] ? df[b,i,j,:]@dist_w[:,h] + dist_b[h] : -1e30
// grid: (b, i, jtile of 128) = 16384 blocks, 256 threads = 16 h x 16 jt.
// blockIdx.x = ((b*512 + i)*4) + tile  ->  tile=bits0-1, i=bits2-10, b=bits11-13.
// Each thread owns ONE head's weight column in 16 float4 REGISTERS (nothing
// for LICM to hoist -> no spill). df tile staged in LDS via coalesced float4
// loads; row stride padded to 68 floats so jt accesses hit distinct bank
// quads (2-way max = free).
__global__ __launch_bounds__(256) void bias_kernel(
    const float* __restrict__ df, const unsigned char* __restrict__ mask8,
    const float* __restrict__ dw, const float* __restrict__ db,
    const int* __restrict__ flag, float* __restrict__ biasb) {
  __shared__ float dfs[128][68];  // 34.8 KB
  const int t    = threadIdx.x;
  const int tile = blockIdx.x & 3;
  const int i    = (blockIdx.x >> 2) & 511;
  const int b    = blockIdx.x >> 11;   // FIXED: was >>13 (b needs bits 11-13)
  const int j0   = tile * 128;
  const int h    = t >> 4;   // 0..15
  const int jt   = t & 15;   // 0..15

  // stage df[(b,i), j0..j0+127, 0..63] -> LDS, coalesced
  const float4* gsrc =
      (const float4*)(df + (((size_t)b * N_ + i) * N_ + j0) * DEMB_);
  #pragma unroll
  for (int s = 0; s < 8; ++s) {
    const int f   = s * 256 + t;       // 0..2047
    const int row = f >> 4, d4 = f & 15;
    *(float4*)&dfs[row][d4 * 4] = gsrc[f];
  }

  // this thread's head column of dist_w (layout [d][h]) -> 16 float4 regs
  float4 w[16];
  #pragma unroll
  for (int d4 = 0; d4 < 16; ++d4) {
    w[d4].x = dw[(d4 * 4 + 0) * HEADS_ + h];
    w[d4].y = dw[(d4 * 4 + 1) * HEADS_ + h];
    w[d4].z = dw[(d4 * 4 + 2) * HEADS_ + h];
    w[d4].w = dw[(d4 * 4 + 3) * HEADS_ + h];
  }
  const float bh = db[h];
  const int fb = *flag;
  const int* mask32 = (const int*)mask8;
  const size_t mbase = ((size_t)b * N_ + i) * N_ + j0;
  float* obase = biasb + (((size_t)b * HEADS_ + h) * N_ + i) * N_ + j0;
  __syncthreads();

  for (int s = 0; s < 8; ++s) {
    const int jl = s * 16 + jt;
    float a0 = 0.f, a1 = 0.f, a2 = 0.f, a3 = 0.f;
    #pragma unroll
    for (int d4 = 0; d4 < 16; ++d4) {
      const float4 v = *(const float4*)&dfs[jl][d4 * 4];
      a0 += v.x * w[d4].x;
      a1 += v.y * w[d4].y;
      a2 += v.z * w[d4].z;
      a3 += v.w * w[d4].w;
    }
    const float acc = (a0 + a1) + (a2 + a3) + bh;
    const bool mv = fb ? (mask8[mbase + jl] != 0) : (mask32[mbase + jl] != 0);
    obase[jl] = mv ? acc : -1e30f;
  }
}

// ---------------- flash attention (fp32, online softmax) ----------------
// block = (b, h, i-half); K/V of one (b,h) staged in LDS (128 KiB).
// One thread per query row i; lockstep over j -> LDS broadcast reads.
__global__ __launch_bounds__(256) void attn_kernel(
    const float* __restrict__ qkv, const float* __restrict__ biasb,
    float* __restrict__ ctx) {
  __shared__ float Ks[N_][HD_];
  __shared__ float Vs[N_][HD_];
  const int t    = threadIdx.x;
  const int b    = blockIdx.x >> 5;
  const int hh   = (blockIdx.x >> 1) & 15;
  const int half = blockIdx.x & 1;
  const size_t qbase = (size_t)b * N_ * (3 * HID_);
  for (int idx = t; idx < N_ * 8; idx += 256) {
    const int j = idx >> 3, f = idx & 7;
    const float* kp = qkv + qbase + (size_t)j * (3 * HID_) + HID_ + hh * HD_ + f * 4;
    *(float4*)&Ks[j][f * 4] = *(const float4*)kp;
    *(float4*)&Vs[j][f * 4] = *(const float4*)(kp + HID_);
  }
  __syncthreads();
  const int i = half * 256 + t;
  const float* qp = qkv + qbase + (size_t)i * (3 * HID_) + hh * HD_;
  float q[HD_];
  #pragma unroll
  for (int f = 0; f < 8; ++f) {
    const float4 v = *(const float4*)(qp + f * 4);
    q[f * 4 + 0] = v.x; q[f * 4 + 1] = v.y; q[f * 4 + 2] = v.z; q[f * 4 + 3] = v.w;
  }
  const float* brow = biasb + (((size_t)b * HEADS_ + hh) * N_ + i) * N_;
  float m = -3.0e38f, l = 0.f;
  float o[HD_];
  #pragma unroll
  for (int d = 0; d < HD_; ++d) o[d] = 0.f;
  for (int j4 = 0; j4 < N_; j4 += 4) {
    const float4 bq = *(const float4*)(brow + j4);
    const float bbv[4] = {bq.x, bq.y, bq.z, bq.w};
    #pragma unroll
    for (int c = 0; c < 4; ++c) {
      const int j = j4 + c;
      float s0 = 0.f, s1 = 0.f, s2 = 0.f, s3 = 0.f;
      #pragma unroll
      for (int d = 0; d < HD_; d += 4) {
        s0 += q[d + 0] * Ks[j][d + 0];
        s1 += q[d + 1] * Ks[j][d + 1];
        s2 += q[d + 2] * Ks[j][d + 2];
        s3 += q[d + 3] * Ks[j][d + 3];
      }
      float s = (s0 + s1) + (s2 + s3);
      s = s * 0.17677669529663687f + bbv[c];  // 1/sqrt(32)
      if (s > m) {
        const float corr = __expf(m - s);
        l *= corr;
        #pragma unroll
        for (int d = 0; d < HD_; ++d) o[d] *= corr;
        m = s;
      }
      const float p = __expf(s - m);
      l += p;
      #pragma unroll
      for (int d = 0; d < HD_; ++d) o[d] += p * Vs[j][d];
    }
  }
  const float inv = 1.0f / l;
  float* cp = ctx + (((size_t)b * N_ + i) * HEADS_ + hh) * HD_;
  #pragma unroll
  for (int f = 0; f < 8; ++f) {
    float4 v;
    v.x = o[f * 4 + 0] * inv; v.y = o[f * 4 + 1] * inv;
    v.z = o[f * 4 + 2] * inv; v.w = o[f * 4 + 3] * inv;
    *(float4*)(cp + f * 4) = v;
  }
}

// ---------------- launcher ----------------
extern "C" void kernel_launch(void* const* d_in, const int* in_sizes, int n_in,
                              void* d_out, int out_size, void* d_ws, size_t ws_size,
                              hipStream_t stream) {
  const float* x      = (const float*)d_in[0];
  const float* df     = (const float*)d_in[1];
  const unsigned char* mask = (const unsigned char*)d_in[2];
  const float* qkv_w  = (const float*)d_in[3];
  const float* qkv_b  = (const float*)d_in[4];
  const float* out_w  = (const float*)d_in[5];
  const float* out_b  = (const float*)d_in[6];
  const float* dist_w = (const float*)d_in[7];
  const float* dist_b = (const float*)d_in[8];
  const float* ln1_g  = (const float*)d_in[9];
  const float* ln1_b  = (const float*)d_in[10];
  const float* ln2_g  = (const float*)d_in[11];
  const float* ln2_b  = (const float*)d_in[12];
  const float* ff1_w  = (const float*)d_in[13];
  const float* ff1_b  = (const float*)d_in[14];
  const float* ff2_w  = (const float*)d_in[15];
  const float* ff2_b  = (const float*)d_in[16];
  float* out = (float*)d_out;

  float* ws    = (float*)d_ws;
  float* h     = ws;                                        // 2,097,152
  float* qkv   = h     + (size_t)ROWS * HID_;               // 6,291,456
  float* biasb = qkv   + (size_t)ROWS * 3 * HID_;           // 33,554,432
  float* ctx   = biasb + (size_t)B_ * HEADS_ * N_ * N_;     // 2,097,152
  float* xa    = ctx   + (size_t)ROWS * HID_;               // 2,097,152
  float* y     = xa    + (size_t)ROWS * HID_;               // 2,097,152
  float* ff1   = y     + (size_t)ROWS * HID_;               // 8,388,608
  int*   flag  = (int*)(ff1 + (size_t)ROWS * FFN_);

  hipMemsetAsync(flag, 0, sizeof(int), stream);
  detect_mask_kernel<<<256, 256, 0, stream>>>(mask, flag);

  // h = LN1(x)
  ln_kernel<<<ROWS / 4, 256, 0, stream>>>(x, ln1_g, ln1_b, h);
  // qkv = h @ qkv_w + qkv_b
  gemm_kernel<0, false><<<dim3(3 * HID_ / 64, ROWS / 64), 256, 0, stream>>>(
      h, qkv_w, qkv_b, nullptr, qkv, 3 * HID_, HID_);
  // biasb = masked distance bias  [B,H,N,N]
  bias_kernel<<<B_ * N_ * 4, 256, 0, stream>>>(df, mask, dist_w, dist_b, flag, biasb);
  // ctx = softmax(QK^T/sqrt(hd) + biasb) @ V
  attn_kernel<<<B_ * HEADS_ * 2, 256, 0, stream>>>(qkv, biasb, ctx);
  // xa = x + ctx @ out_w + out_b
  gemm_kernel<0, true><<<dim3(HID_ / 64, ROWS / 64), 256, 0, stream>>>(
      ctx, out_w, out_b, x, xa, HID_, HID_);
  // y = LN2(xa)
  ln_kernel<<<ROWS / 4, 256, 0, stream>>>(xa, ln2_g, ln2_b, y);
  // ff1 = gelu(y @ ff1_w + ff1_b)
  gemm_kernel<1, false><<<dim3(FFN_ / 64, ROWS / 64), 256, 0, stream>>>(
      y, ff1_w, ff1_b, nullptr, ff1, FFN_, HID_);
  // out = xa + ff1 @ ff2_w + ff2_b
  gemm_kernel<0, true><<<dim3(HID_ / 64, ROWS / 64), 256, 0, stream>>>(
      ff1, ff2_w, ff2_b, xa, out, HID_, FFN_);
}

// Round 4
// 538.777 us; speedup vs baseline: 5.3911x; 1.5779x over previous
//
#include <hip/hip_runtime.h>
#include <cstddef>
#include <cstdint>

#define B_     8
#define N_     512
#define HID_   512
#define HEADS_ 16
#define HD_    32
#define FFN_   2048
#define DEMB_  64
#define ROWS   (B_*N_)   // 4096

typedef unsigned short u16;
typedef short bf16x8 __attribute__((ext_vector_type(8)));
typedef float f32x4  __attribute__((ext_vector_type(4)));
typedef short short8v __attribute__((ext_vector_type(8)));

__device__ __forceinline__ u16 f2bf(float f) {   // RNE float->bf16
  unsigned u = __float_as_uint(f);
  u += 0x7fffu + ((u >> 16) & 1u);
  return (u16)(u >> 16);
}

__device__ __forceinline__ void gload16(const void* g, void* l) {
  // async global->LDS, 16B/lane; LDS dest = wave-uniform base + lane*16
  __builtin_amdgcn_global_load_lds(
      (const __attribute__((address_space(1))) unsigned int*)g,
      (__attribute__((address_space(3))) unsigned int*)l, 16, 0, 0);
}

// ---------------- edge_mask dtype detection ----------------
__global__ void detect_mask_kernel(const unsigned char* __restrict__ m,
                                   int* __restrict__ flag) {
  int t = blockIdx.x * blockDim.x + threadIdx.x;  // 65536 threads
  if ((t & 3) != 0) {
    if (m[t] != 0) atomicOr(flag, 1);
  }
}

// ---------------- LayerNorm (fp32 in -> bf16 out): one wave per row ----------------
__global__ __launch_bounds__(256) void ln_kernel(const float* __restrict__ x,
                                                 const float* __restrict__ g,
                                                 const float* __restrict__ bt,
                                                 u16* __restrict__ y) {
  const int lane = threadIdx.x & 63;
  const int row  = blockIdx.x * 4 + (threadIdx.x >> 6);
  const float* xr = x + (size_t)row * HID_;
  float4 v0 = *(const float4*)(xr + lane * 8);
  float4 v1 = *(const float4*)(xr + lane * 8 + 4);
  float s = v0.x + v0.y + v0.z + v0.w + v1.x + v1.y + v1.z + v1.w;
  float q = v0.x*v0.x + v0.y*v0.y + v0.z*v0.z + v0.w*v0.w
          + v1.x*v1.x + v1.y*v1.y + v1.z*v1.z + v1.w*v1.w;
  #pragma unroll
  for (int off = 32; off > 0; off >>= 1) {
    s += __shfl_xor(s, off, 64);
    q += __shfl_xor(q, off, 64);
  }
  const float mean = s * (1.0f / HID_);
  const float var  = q * (1.0f / HID_) - mean * mean;
  const float rs   = rsqrtf(var + 1e-5f);
  const float4 g0 = *(const float4*)(g + lane * 8);
  const float4 g1 = *(const float4*)(g + lane * 8 + 4);
  const float4 b0 = *(const float4*)(bt + lane * 8);
  const float4 b1 = *(const float4*)(bt + lane * 8 + 4);
  short8v o;
  o[0] = (short)f2bf((v0.x - mean) * rs * g0.x + b0.x);
  o[1] = (short)f2bf((v0.y - mean) * rs * g0.y + b0.y);
  o[2] = (short)f2bf((v0.z - mean) * rs * g0.z + b0.z);
  o[3] = (short)f2bf((v0.w - mean) * rs * g0.w + b0.w);
  o[4] = (short)f2bf((v1.x - mean) * rs * g1.x + b1.x);
  o[5] = (short)f2bf((v1.y - mean) * rs * g1.y + b1.y);
  o[6] = (short)f2bf((v1.z - mean) * rs * g1.z + b1.z);
  o[7] = (short)f2bf((v1.w - mean) * rs * g1.w + b1.w);
  *(short8v*)(y + (size_t)row * HID_ + lane * 8) = o;
}

// ---------------- weight transpose-cast: W[K][N] f32 -> Wt[N][K] bf16 ----------------
__global__ __launch_bounds__(256) void wt_kernel(const float* __restrict__ W,
                                                 u16* __restrict__ Wt,
                                                 int K, int N) {
  __shared__ float tile[32][33];
  const int t = threadIdx.x;
  const int n0 = blockIdx.x * 32, k0 = blockIdx.y * 32;
  const int tx = t & 31, ty = t >> 5;  // ty 0..7
  #pragma unroll
  for (int i = 0; i < 4; ++i)
    tile[ty + 8 * i][tx] = W[(size_t)(k0 + ty + 8 * i) * N + n0 + tx];
  __syncthreads();
  #pragma unroll
  for (int i = 0; i < 4; ++i) {
    const int n = ty + 8 * i;
    Wt[(size_t)(n0 + n) * K + k0 + tx] = f2bf(tile[tx][n]);
  }
}

// ---------------- bf16 MFMA GEMM: C = act(A@W + bias) (+res) ----------------
// A[M][K] bf16 row-major; Wt[N][K] bf16 (= W transposed). 128x128 tile, BK=64,
// 256 thr = 4 waves (2x2 of 64x64), mfma_f32_16x16x32_bf16, fp32 accum.
// LDS linear [row][64k]; XOR swizzle (slot ^= row&7) applied on the GLOBAL
// source during global_load_lds staging and on the ds_read address (rule #21).
// ACT: 0 none, 1 exact GELU. HAS_RES: += res. OUT_BF16: write bf16 else f32.
template <int ACT, bool HAS_RES, bool OUT_BF16>
__global__ __launch_bounds__(256) void mfma_gemm(
    const u16* __restrict__ A, const u16* __restrict__ Wt,
    const float* __restrict__ bias, const float* __restrict__ res,
    void* __restrict__ Cout, int N, int K) {
  __shared__ __align__(16) u16 As[128 * 64];
  __shared__ __align__(16) u16 Bs[128 * 64];
  const int t    = threadIdx.x;
  const int wid  = t >> 6, lane = t & 63;
  const int wr   = wid >> 1, wc = wid & 1;      // wave -> 64x64 quadrant
  const int m0   = blockIdx.y * 128, n0 = blockIdx.x * 128;
  // staging maps: each wave stages rows wid*32 .. wid*32+31 (4 insts of 8 rows)
  const int srow8 = lane >> 3;                  // 0..7 (= row&7 of the 8-row group)
  const int sslot = (lane & 7) ^ srow8;         // inverse-swizzled k-slot (involution)

  f32x4 zero = {0.f, 0.f, 0.f, 0.f};
  f32x4 acc[4][4];
  #pragma unroll
  for (int m = 0; m < 4; ++m)
    #pragma unroll
    for (int n = 0; n < 4; ++n) acc[m][n] = zero;

  for (int kt = 0; kt < K; kt += 64) {
    __syncthreads();   // previous compute done before overwriting LDS
    #pragma unroll
    for (int i = 0; i < 4; ++i) {
      const int rbase = wid * 32 + i * 8;
      const int r = rbase + srow8;
      gload16(A  + (size_t)(m0 + r) * K + kt + sslot * 8, &As[rbase * 64]);
      gload16(Wt + (size_t)(n0 + r) * K + kt + sslot * 8, &Bs[rbase * 64]);
    }
    __syncthreads();   // drains vmcnt(0) before barrier
    #pragma unroll
    for (int kk = 0; kk < 2; ++kk) {
      bf16x8 a[4], b[4];
      #pragma unroll
      for (int m = 0; m < 4; ++m) {
        const int row = wr * 64 + m * 16 + (lane & 15);
        const int s   = (kk * 4 + (lane >> 4)) ^ (row & 7);
        a[m] = *(const bf16x8*)&As[row * 64 + s * 8];
      }
      #pragma unroll
      for (int n = 0; n < 4; ++n) {
        const int row = wc * 64 + n * 16 + (lane & 15);
        const int s   = (kk * 4 + (lane >> 4)) ^ (row & 7);
        b[n] = *(const bf16x8*)&Bs[row * 64 + s * 8];
      }
      #pragma unroll
      for (int m = 0; m < 4; ++m)
        #pragma unroll
        for (int n = 0; n < 4; ++n)
          acc[m][n] = __builtin_amdgcn_mfma_f32_16x16x32_bf16(
              a[m], b[n], acc[m][n], 0, 0, 0);
    }
  }
  // epilogue: C/D layout col=lane&15, row=(lane>>4)*4+reg (m89-verified)
  #pragma unroll
  for (int n = 0; n < 4; ++n) {
    const int col = n0 + wc * 64 + n * 16 + (lane & 15);
    const float bb = bias[col];
    #pragma unroll
    for (int m = 0; m < 4; ++m) {
      #pragma unroll
      for (int j = 0; j < 4; ++j) {
        const int row = m0 + wr * 64 + m * 16 + (lane >> 4) * 4 + j;
        float v = acc[m][n][j] + bb;
        if (ACT == 1) v = 0.5f * v * (1.0f + erff(v * 0.70710678118654752f));
        const size_t off = (size_t)row * N + col;
        if (HAS_RES) v += res[off];
        if (OUT_BF16) ((u16*)Cout)[off] = f2bf(v);
        else          ((float*)Cout)[off] = v;
      }
    }
  }
}

// ---------------- fused distance-bias + mask ----------------
__global__ __launch_bounds__(256) void bias_kernel(
    const float* __restrict__ df, const unsigned char* __restrict__ mask8,
    const float* __restrict__ dw, const float* __restrict__ db,
    const int* __restrict__ flag, float* __restrict__ biasb) {
  __shared__ float dfs[128][68];  // 34.8 KB
  const int t    = threadIdx.x;
  const int tile = blockIdx.x & 3;
  const int i    = (blockIdx.x >> 2) & 511;
  const int b    = blockIdx.x >> 11;
  const int j0   = tile * 128;
  const int h    = t >> 4;   // 0..15
  const int jt   = t & 15;   // 0..15

  const float4* gsrc =
      (const float4*)(df + (((size_t)b * N_ + i) * N_ + j0) * DEMB_);
  #pragma unroll
  for (int s = 0; s < 8; ++s) {
    const int f   = s * 256 + t;       // 0..2047
    const int row = f >> 4, d4 = f & 15;
    *(float4*)&dfs[row][d4 * 4] = gsrc[f];
  }

  float4 w[16];
  #pragma unroll
  for (int d4 = 0; d4 < 16; ++d4) {
    w[d4].x = dw[(d4 * 4 + 0) * HEADS_ + h];
    w[d4].y = dw[(d4 * 4 + 1) * HEADS_ + h];
    w[d4].z = dw[(d4 * 4 + 2) * HEADS_ + h];
    w[d4].w = dw[(d4 * 4 + 3) * HEADS_ + h];
  }
  const float bh = db[h];
  const int fb = *flag;
  const int* mask32 = (const int*)mask8;
  const size_t mbase = ((size_t)b * N_ + i) * N_ + j0;
  float* obase = biasb + (((size_t)b * HEADS_ + h) * N_ + i) * N_ + j0;
  __syncthreads();

  for (int s = 0; s < 8; ++s) {
    const int jl = s * 16 + jt;
    float a0 = 0.f, a1 = 0.f, a2 = 0.f, a3 = 0.f;
    #pragma unroll
    for (int d4 = 0; d4 < 16; ++d4) {
      const float4 v = *(const float4*)&dfs[jl][d4 * 4];
      a0 += v.x * w[d4].x;
      a1 += v.y * w[d4].y;
      a2 += v.z * w[d4].z;
      a3 += v.w * w[d4].w;
    }
    const float acc = (a0 + a1) + (a2 + a3) + bh;
    const bool mv = fb ? (mask8[mbase + jl] != 0) : (mask32[mbase + jl] != 0);
    obase[jl] = mv ? acc : -1e30f;
  }
}

// ---------------- flash attention (fp32 math, bf16 ctx out) ----------------
__global__ __launch_bounds__(256) void attn_kernel(
    const float* __restrict__ qkv, const float* __restrict__ biasb,
    u16* __restrict__ ctx) {
  __shared__ float Ks[N_][HD_];
  __shared__ float Vs[N_][HD_];
  const int t    = threadIdx.x;
  const int b    = blockIdx.x >> 5;
  const int hh   = (blockIdx.x >> 1) & 15;
  const int half = blockIdx.x & 1;
  const size_t qbase = (size_t)b * N_ * (3 * HID_);
  for (int idx = t; idx < N_ * 8; idx += 256) {
    const int j = idx >> 3, f = idx & 7;
    const float* kp = qkv + qbase + (size_t)j * (3 * HID_) + HID_ + hh * HD_ + f * 4;
    *(float4*)&Ks[j][f * 4] = *(const float4*)kp;
    *(float4*)&Vs[j][f * 4] = *(const float4*)(kp + HID_);
  }
  __syncthreads();
  const int i = half * 256 + t;
  const float* qp = qkv + qbase + (size_t)i * (3 * HID_) + hh * HD_;
  float q[HD_];
  #pragma unroll
  for (int f = 0; f < 8; ++f) {
    const float4 v = *(const float4*)(qp + f * 4);
    q[f * 4 + 0] = v.x; q[f * 4 + 1] = v.y; q[f * 4 + 2] = v.z; q[f * 4 + 3] = v.w;
  }
  const float* brow = biasb + (((size_t)b * HEADS_ + hh) * N_ + i) * N_;
  float m = -3.0e38f, l = 0.f;
  float o[HD_];
  #pragma unroll
  for (int d = 0; d < HD_; ++d) o[d] = 0.f;
  for (int j4 = 0; j4 < N_; j4 += 4) {
    const float4 bq = *(const float4*)(brow + j4);
    const float bbv[4] = {bq.x, bq.y, bq.z, bq.w};
    #pragma unroll
    for (int c = 0; c < 4; ++c) {
      const int j = j4 + c;
      float s0 = 0.f, s1 = 0.f, s2 = 0.f, s3 = 0.f;
      #pragma unroll
      for (int d = 0; d < HD_; d += 4) {
        s0 += q[d + 0] * Ks[j][d + 0];
        s1 += q[d + 1] * Ks[j][d + 1];
        s2 += q[d + 2] * Ks[j][d + 2];
        s3 += q[d + 3] * Ks[j][d + 3];
      }
      float s = (s0 + s1) + (s2 + s3);
      s = s * 0.17677669529663687f + bbv[c];  // 1/sqrt(32)
      if (s > m) {
        const float corr = __expf(m - s);
        l *= corr;
        #pragma unroll
        for (int d = 0; d < HD_; ++d) o[d] *= corr;
        m = s;
      }
      const float p = __expf(s - m);
      l += p;
      #pragma unroll
      for (int d = 0; d < HD_; ++d) o[d] += p * Vs[j][d];
    }
  }
  const float inv = 1.0f / l;
  u16* cp = ctx + (((size_t)b * N_ + i) * HEADS_ + hh) * HD_;
  #pragma unroll
  for (int f = 0; f < 4; ++f) {
    short8v v;
    #pragma unroll
    for (int e = 0; e < 8; ++e) v[e] = (short)f2bf(o[f * 8 + e] * inv);
    *(short8v*)(cp + f * 8) = v;
  }
}

// ---------------- launcher ----------------
extern "C" void kernel_launch(void* const* d_in, const int* in_sizes, int n_in,
                              void* d_out, int out_size, void* d_ws, size_t ws_size,
                              hipStream_t stream) {
  const float* x      = (const float*)d_in[0];
  const float* df     = (const float*)d_in[1];
  const unsigned char* mask = (const unsigned char*)d_in[2];
  const float* qkv_w  = (const float*)d_in[3];
  const float* qkv_b  = (const float*)d_in[4];
  const float* out_w  = (const float*)d_in[5];
  const float* out_b  = (const float*)d_in[6];
  const float* dist_w = (const float*)d_in[7];
  const float* dist_b = (const float*)d_in[8];
  const float* ln1_g  = (const float*)d_in[9];
  const float* ln1_b  = (const float*)d_in[10];
  const float* ln2_g  = (const float*)d_in[11];
  const float* ln2_b  = (const float*)d_in[12];
  const float* ff1_w  = (const float*)d_in[13];
  const float* ff1_b  = (const float*)d_in[14];
  const float* ff2_w  = (const float*)d_in[15];
  const float* ff2_b  = (const float*)d_in[16];
  float* out = (float*)d_out;

  char* p = (char*)d_ws;
  auto alloc = [&](size_t bytes) {
    char* r = p;
    p += (bytes + 255) & ~(size_t)255;
    return r;
  };
  float* qkv    = (float*)alloc((size_t)ROWS * 3 * HID_ * 4);
  float* biasb  = (float*)alloc((size_t)B_ * HEADS_ * N_ * N_ * 4);
  float* xa     = (float*)alloc((size_t)ROWS * HID_ * 4);
  u16*   h16    = (u16*)alloc((size_t)ROWS * HID_ * 2);
  u16*   ctx16  = (u16*)alloc((size_t)ROWS * HID_ * 2);
  u16*   y16    = (u16*)alloc((size_t)ROWS * HID_ * 2);
  u16*   ff116  = (u16*)alloc((size_t)ROWS * FFN_ * 2);
  u16*   qkv_wt = (u16*)alloc((size_t)3 * HID_ * HID_ * 2);
  u16*   out_wt = (u16*)alloc((size_t)HID_ * HID_ * 2);
  u16*   ff1_wt = (u16*)alloc((size_t)FFN_ * HID_ * 2);
  u16*   ff2_wt = (u16*)alloc((size_t)HID_ * FFN_ * 2);
  int*   flag   = (int*)alloc(sizeof(int));

  hipMemsetAsync(flag, 0, sizeof(int), stream);
  detect_mask_kernel<<<256, 256, 0, stream>>>(mask, flag);

  // weight transpose-casts (Wt[N][K] bf16)
  wt_kernel<<<dim3(3 * HID_ / 32, HID_ / 32), 256, 0, stream>>>(qkv_w, qkv_wt, HID_, 3 * HID_);
  wt_kernel<<<dim3(HID_ / 32, HID_ / 32), 256, 0, stream>>>(out_w, out_wt, HID_, HID_);
  wt_kernel<<<dim3(FFN_ / 32, HID_ / 32), 256, 0, stream>>>(ff1_w, ff1_wt, HID_, FFN_);
  wt_kernel<<<dim3(HID_ / 32, FFN_ / 32), 256, 0, stream>>>(ff2_w, ff2_wt, FFN_, HID_);

  // h16 = bf16(LN1(x))
  ln_kernel<<<ROWS / 4, 256, 0, stream>>>(x, ln1_g, ln1_b, h16);
  // qkv = h @ qkv_w + qkv_b   (f32 out)
  mfma_gemm<0, false, false><<<dim3(3 * HID_ / 128, ROWS / 128), 256, 0, stream>>>(
      h16, qkv_wt, qkv_b, nullptr, qkv, 3 * HID_, HID_);
  // biasb = masked distance bias [B,H,N,N]
  bias_kernel<<<B_ * N_ * 4, 256, 0, stream>>>(df, mask, dist_w, dist_b, flag, biasb);
  // ctx16 = bf16(softmax(QK^T/sqrt(hd) + biasb) @ V)
  attn_kernel<<<B_ * HEADS_ * 2, 256, 0, stream>>>(qkv, biasb, ctx16);
  // xa = x + ctx @ out_w + out_b   (f32 out)
  mfma_gemm<0, true, false><<<dim3(HID_ / 128, ROWS / 128), 256, 0, stream>>>(
      ctx16, out_wt, out_b, x, xa, HID_, HID_);
  // y16 = bf16(LN2(xa))
  ln_kernel<<<ROWS / 4, 256, 0, stream>>>(xa, ln2_g, ln2_b, y16);
  // ff116 = bf16(gelu(y @ ff1_w + ff1_b))
  mfma_gemm<1, false, true><<<dim3(FFN_ / 128, ROWS / 128), 256, 0, stream>>>(
      y16, ff1_wt, ff1_b, nullptr, ff116, FFN_, HID_);
  // out = xa + ff1 @ ff2_w + ff2_b   (f32 out)
  mfma_gemm<0, true, false><<<dim3(HID_ / 128, ROWS / 128), 256, 0, stream>>>(
      ff116, ff2_wt, ff2_b, xa, out, HID_, FFN_);
}

// Round 5
// 529.785 us; speedup vs baseline: 5.4826x; 1.0170x over previous
//
#include <hip/hip_runtime.h>
#include <cstddef>
#include <cstdint>

#define B_     8
#define N_     512
#define HID_   512
#define HEADS_ 16
#define HD_    32
#define FFN_   2048
#define DEMB_  64
#define ROWS   (B_*N_)   // 4096

typedef unsigned short u16;
typedef short bf16x8 __attribute__((ext_vector_type(8)));
typedef float f32x4  __attribute__((ext_vector_type(4)));
typedef short short8v __attribute__((ext_vector_type(8)));
typedef short short4v __attribute__((ext_vector_type(4)));

__device__ __forceinline__ u16 f2bf(float f) {   // RNE float->bf16
  unsigned u = __float_as_uint(f);
  u += 0x7fffu + ((u >> 16) & 1u);
  return (u16)(u >> 16);
}
__device__ __forceinline__ float bf2f(u16 b) {
  return __uint_as_float(((unsigned)b) << 16);
}

__device__ __forceinline__ void gload16(const void* g, void* l) {
  // async global->LDS, 16B/lane; LDS dest = wave-uniform base + lane*16
  __builtin_amdgcn_global_load_lds(
      (const __attribute__((address_space(1))) unsigned int*)g,
      (__attribute__((address_space(3))) unsigned int*)l, 16, 0, 0);
}

// ---------------- edge_mask dtype detection ----------------
__global__ void detect_mask_kernel(const unsigned char* __restrict__ m,
                                   int* __restrict__ flag) {
  int t = blockIdx.x * blockDim.x + threadIdx.x;  // 65536 threads
  if ((t & 3) != 0) {
    if (m[t] != 0) atomicOr(flag, 1);
  }
}

// ---------------- LayerNorm (fp32 in -> bf16 out): one wave per row ----------------
__global__ __launch_bounds__(256) void ln_kernel(const float* __restrict__ x,
                                                 const float* __restrict__ g,
                                                 const float* __restrict__ bt,
                                                 u16* __restrict__ y) {
  const int lane = threadIdx.x & 63;
  const int row  = blockIdx.x * 4 + (threadIdx.x >> 6);
  const float* xr = x + (size_t)row * HID_;
  float4 v0 = *(const float4*)(xr + lane * 8);
  float4 v1 = *(const float4*)(xr + lane * 8 + 4);
  float s = v0.x + v0.y + v0.z + v0.w + v1.x + v1.y + v1.z + v1.w;
  float q = v0.x*v0.x + v0.y*v0.y + v0.z*v0.z + v0.w*v0.w
          + v1.x*v1.x + v1.y*v1.y + v1.z*v1.z + v1.w*v1.w;
  #pragma unroll
  for (int off = 32; off > 0; off >>= 1) {
    s += __shfl_xor(s, off, 64);
    q += __shfl_xor(q, off, 64);
  }
  const float mean = s * (1.0f / HID_);
  const float var  = q * (1.0f / HID_) - mean * mean;
  const float rs   = rsqrtf(var + 1e-5f);
  const float4 g0 = *(const float4*)(g + lane * 8);
  const float4 g1 = *(const float4*)(g + lane * 8 + 4);
  const float4 b0 = *(const float4*)(bt + lane * 8);
  const float4 b1 = *(const float4*)(bt + lane * 8 + 4);
  short8v o;
  o[0] = (short)f2bf((v0.x - mean) * rs * g0.x + b0.x);
  o[1] = (short)f2bf((v0.y - mean) * rs * g0.y + b0.y);
  o[2] = (short)f2bf((v0.z - mean) * rs * g0.z + b0.z);
  o[3] = (short)f2bf((v0.w - mean) * rs * g0.w + b0.w);
  o[4] = (short)f2bf((v1.x - mean) * rs * g1.x + b1.x);
  o[5] = (short)f2bf((v1.y - mean) * rs * g1.y + b1.y);
  o[6] = (short)f2bf((v1.z - mean) * rs * g1.z + b1.z);
  o[7] = (short)f2bf((v1.w - mean) * rs * g1.w + b1.w);
  *(short8v*)(y + (size_t)row * HID_ + lane * 8) = o;
}

// ---------------- weight transpose-cast: W[K][N] f32 -> Wt[N][K] bf16 ----------------
__global__ __launch_bounds__(256) void wt_kernel(const float* __restrict__ W,
                                                 u16* __restrict__ Wt,
                                                 int K, int N) {
  __shared__ float tile[32][33];
  const int t = threadIdx.x;
  const int n0 = blockIdx.x * 32, k0 = blockIdx.y * 32;
  const int tx = t & 31, ty = t >> 5;  // ty 0..7
  #pragma unroll
  for (int i = 0; i < 4; ++i)
    tile[ty + 8 * i][tx] = W[(size_t)(k0 + ty + 8 * i) * N + n0 + tx];
  __syncthreads();
  #pragma unroll
  for (int i = 0; i < 4; ++i) {
    const int n = ty + 8 * i;
    Wt[(size_t)(n0 + n) * K + k0 + tx] = f2bf(tile[tx][n]);
  }
}

// ---------------- bf16 MFMA GEMM: C = act(A@W + bias) (+res) ----------------
// A[M][K] bf16 row-major; Wt[N][K] bf16 (= W transposed). 128x128 tile, BK=64,
// 256 thr = 4 waves (2x2 of 64x64), mfma_f32_16x16x32_bf16, fp32 accum.
// LDS linear [row][64k]; XOR swizzle (slot ^= row&7) applied on the GLOBAL
// source during global_load_lds staging and on the ds_read address (rule #21).
// ACT: 0 none, 1 exact GELU. HAS_RES: += res. OUT_BF16: write bf16 else f32.
template <int ACT, bool HAS_RES, bool OUT_BF16>
__global__ __launch_bounds__(256) void mfma_gemm(
    const u16* __restrict__ A, const u16* __restrict__ Wt,
    const float* __restrict__ bias, const float* __restrict__ res,
    void* __restrict__ Cout, int N, int K) {
  __shared__ __align__(16) u16 As[128 * 64];
  __shared__ __align__(16) u16 Bs[128 * 64];
  const int t    = threadIdx.x;
  const int wid  = t >> 6, lane = t & 63;
  const int wr   = wid >> 1, wc = wid & 1;      // wave -> 64x64 quadrant
  const int m0   = blockIdx.y * 128, n0 = blockIdx.x * 128;
  // staging maps: each wave stages rows wid*32 .. wid*32+31 (4 insts of 8 rows)
  const int srow8 = lane >> 3;                  // 0..7 (= row&7 of the 8-row group)
  const int sslot = (lane & 7) ^ srow8;         // inverse-swizzled k-slot (involution)

  f32x4 zero = {0.f, 0.f, 0.f, 0.f};
  f32x4 acc[4][4];
  #pragma unroll
  for (int m = 0; m < 4; ++m)
    #pragma unroll
    for (int n = 0; n < 4; ++n) acc[m][n] = zero;

  for (int kt = 0; kt < K; kt += 64) {
    __syncthreads();   // previous compute done before overwriting LDS
    #pragma unroll
    for (int i = 0; i < 4; ++i) {
      const int rbase = wid * 32 + i * 8;
      const int r = rbase + srow8;
      gload16(A  + (size_t)(m0 + r) * K + kt + sslot * 8, &As[rbase * 64]);
      gload16(Wt + (size_t)(n0 + r) * K + kt + sslot * 8, &Bs[rbase * 64]);
    }
    __syncthreads();   // drains vmcnt(0) before barrier
    #pragma unroll
    for (int kk = 0; kk < 2; ++kk) {
      bf16x8 a[4], b[4];
      #pragma unroll
      for (int m = 0; m < 4; ++m) {
        const int row = wr * 64 + m * 16 + (lane & 15);
        const int s   = (kk * 4 + (lane >> 4)) ^ (row & 7);
        a[m] = *(const bf16x8*)&As[row * 64 + s * 8];
      }
      #pragma unroll
      for (int n = 0; n < 4; ++n) {
        const int row = wc * 64 + n * 16 + (lane & 15);
        const int s   = (kk * 4 + (lane >> 4)) ^ (row & 7);
        b[n] = *(const bf16x8*)&Bs[row * 64 + s * 8];
      }
      #pragma unroll
      for (int m = 0; m < 4; ++m)
        #pragma unroll
        for (int n = 0; n < 4; ++n)
          acc[m][n] = __builtin_amdgcn_mfma_f32_16x16x32_bf16(
              a[m], b[n], acc[m][n], 0, 0, 0);
    }
  }
  // epilogue: C/D layout col=lane&15, row=(lane>>4)*4+reg (m89-verified)
  #pragma unroll
  for (int n = 0; n < 4; ++n) {
    const int col = n0 + wc * 64 + n * 16 + (lane & 15);
    const float bb = bias[col];
    #pragma unroll
    for (int m = 0; m < 4; ++m) {
      #pragma unroll
      for (int j = 0; j < 4; ++j) {
        const int row = m0 + wr * 64 + m * 16 + (lane >> 4) * 4 + j;
        float v = acc[m][n][j] + bb;
        if (ACT == 1) v = 0.5f * v * (1.0f + erff(v * 0.70710678118654752f));
        const size_t off = (size_t)row * N + col;
        if (HAS_RES) v += res[off];
        if (OUT_BF16) ((u16*)Cout)[off] = f2bf(v);
        else          ((float*)Cout)[off] = v;
      }
    }
  }
}

// ---------------- fused distance-bias + mask (bf16 out) ----------------
// biasb[b,h,i,j] = bf16(mask ? df@dist_w + dist_b : -1e30)
__global__ __launch_bounds__(256) void bias_kernel(
    const float* __restrict__ df, const unsigned char* __restrict__ mask8,
    const float* __restrict__ dw, const float* __restrict__ db,
    const int* __restrict__ flag, u16* __restrict__ biasb) {
  __shared__ float dfs[128][68];  // 34.8 KB
  const int t    = threadIdx.x;
  const int tile = blockIdx.x & 3;
  const int i    = (blockIdx.x >> 2) & 511;
  const int b    = blockIdx.x >> 11;
  const int j0   = tile * 128;
  const int h    = t >> 4;   // 0..15
  const int jt   = t & 15;   // 0..15

  const float4* gsrc =
      (const float4*)(df + (((size_t)b * N_ + i) * N_ + j0) * DEMB_);
  #pragma unroll
  for (int s = 0; s < 8; ++s) {
    const int f   = s * 256 + t;       // 0..2047
    const int row = f >> 4, d4 = f & 15;
    *(float4*)&dfs[row][d4 * 4] = gsrc[f];
  }

  float4 w[16];
  #pragma unroll
  for (int d4 = 0; d4 < 16; ++d4) {
    w[d4].x = dw[(d4 * 4 + 0) * HEADS_ + h];
    w[d4].y = dw[(d4 * 4 + 1) * HEADS_ + h];
    w[d4].z = dw[(d4 * 4 + 2) * HEADS_ + h];
    w[d4].w = dw[(d4 * 4 + 3) * HEADS_ + h];
  }
  const float bh = db[h];
  const int fb = *flag;
  const int* mask32 = (const int*)mask8;
  const size_t mbase = ((size_t)b * N_ + i) * N_ + j0;
  u16* obase = biasb + (((size_t)b * HEADS_ + h) * N_ + i) * N_ + j0;
  __syncthreads();

  for (int s = 0; s < 8; ++s) {
    const int jl = s * 16 + jt;
    float a0 = 0.f, a1 = 0.f, a2 = 0.f, a3 = 0.f;
    #pragma unroll
    for (int d4 = 0; d4 < 16; ++d4) {
      const float4 v = *(const float4*)&dfs[jl][d4 * 4];
      a0 += v.x * w[d4].x;
      a1 += v.y * w[d4].y;
      a2 += v.z * w[d4].z;
      a3 += v.w * w[d4].w;
    }
    const float acc = (a0 + a1) + (a2 + a3) + bh;
    const bool mv = fb ? (mask8[mbase + jl] != 0) : (mask32[mbase + jl] != 0);
    obase[jl] = f2bf(mv ? acc : -1e30f);
  }
}

// ---------------- flash attention v3 ----------------
// grid = (b, h, iblk of 64 rows) = 1024 blocks; 256 thr = 4 waves.
// Wave jq handles j in [jq*128, jq*128+128) for all 64 rows (lane = row).
// K staged bf16 in LDS (32 KB, broadcast reads); V read from global f32
// (wave-uniform address -> L1 broadcast); bias read bf16 per-lane.
// Online softmax with defer-max (THR=8); 4 partials combined via LDS union.
__global__ __launch_bounds__(256) void attn_kernel(
    const float* __restrict__ qkv, const u16* __restrict__ biasb,
    u16* __restrict__ ctx) {
  __shared__ union {
    u16 k[N_ * HD_];               // 32 KB  Ks[j][d]
    struct {
      float po[3][64][33];         // +1 pad -> conflict-free combine
      float pm[3][64];
      float pl[3][64];
    } c;
  } sm;
  const int t    = threadIdx.x;
  const int bx   = blockIdx.x;
  const int b    = bx >> 7;
  const int h    = (bx >> 3) & 15;
  const int iblk = bx & 7;
  const int jq   = t >> 6;         // wave id = j-quarter
  const int r    = t & 63;         // lane = row within block
  const int i    = iblk * 64 + r;
  const size_t qbase = (size_t)b * N_ * (3 * HID_);

  // stage K[all j][32] as bf16 (coalesced float4 reads)
  for (int idx = t; idx < N_ * 8; idx += 256) {
    const int j = idx >> 3, f = idx & 7;
    const float4 kv = *(const float4*)(qkv + qbase + (size_t)j * (3 * HID_) +
                                       HID_ + h * HD_ + f * 4);
    short4v ks;
    ks[0] = (short)f2bf(kv.x); ks[1] = (short)f2bf(kv.y);
    ks[2] = (short)f2bf(kv.z); ks[3] = (short)f2bf(kv.w);
    *(short4v*)&sm.k[j * HD_ + f * 4] = ks;
  }
  __syncthreads();

  // q regs, pre-scaled by 1/sqrt(HD)
  float q[HD_];
  {
    const float* qp = qkv + qbase + (size_t)i * (3 * HID_) + h * HD_;
    #pragma unroll
    for (int f = 0; f < 8; ++f) {
      const float4 v = *(const float4*)(qp + f * 4);
      q[f*4+0] = v.x * 0.17677669529663687f;
      q[f*4+1] = v.y * 0.17677669529663687f;
      q[f*4+2] = v.z * 0.17677669529663687f;
      q[f*4+3] = v.w * 0.17677669529663687f;
    }
  }
  const u16* brow = biasb + (((size_t)b * HEADS_ + h) * N_ + i) * N_ + jq * 128;
  const float* vbase = qkv + qbase + 2 * HID_ + h * HD_;
  float m = -3.0e38f, l = 0.f;
  float o[HD_];
  #pragma unroll
  for (int d = 0; d < HD_; ++d) o[d] = 0.f;

  for (int j8 = 0; j8 < 128; j8 += 8) {
    const short8v bq = *(const short8v*)(brow + j8);
    #pragma unroll
    for (int e = 0; e < 8; ++e) {
      const int j = jq * 128 + j8 + e;
      const u16* kr = &sm.k[j * HD_];
      float s = 0.f;
      #pragma unroll
      for (int c = 0; c < 4; ++c) {
        const short8v kk = *(const short8v*)(kr + c * 8);
        #pragma unroll
        for (int d = 0; d < 8; ++d)
          s += q[c*8+d] * bf2f((u16)kk[d]);
      }
      s += bf2f((u16)bq[e]);
      if (s - m > 8.0f) {                  // defer-max (T13)
        const float corr = __expf(m - s);
        l *= corr;
        #pragma unroll
        for (int d = 0; d < HD_; ++d) o[d] *= corr;
        m = s;
      }
      const float p = __expf(s - m);
      l += p;
      const float4* vr = (const float4*)(vbase + (size_t)j * (3 * HID_));
      #pragma unroll
      for (int c = 0; c < 8; ++c) {
        const float4 vv = vr[c];
        o[c*4+0] += p * vv.x; o[c*4+1] += p * vv.y;
        o[c*4+2] += p * vv.z; o[c*4+3] += p * vv.w;
      }
    }
  }

  __syncthreads();                  // Ks dead; LDS reused for combine
  if (jq > 0) {
    sm.c.pm[jq-1][r] = m;
    sm.c.pl[jq-1][r] = l;
    #pragma unroll
    for (int d = 0; d < HD_; ++d) sm.c.po[jq-1][r][d] = o[d];
  }
  __syncthreads();
  if (jq == 0) {
    #pragma unroll
    for (int p2 = 0; p2 < 3; ++p2) {
      const float m2 = sm.c.pm[p2][r], l2 = sm.c.pl[p2][r];
      const float mn = fmaxf(m, m2);
      const float c1 = __expf(m - mn), c2 = __expf(m2 - mn);
      l = l * c1 + l2 * c2;
      #pragma unroll
      for (int d = 0; d < HD_; ++d)
        o[d] = o[d] * c1 + sm.c.po[p2][r][d] * c2;
      m = mn;
    }
    const float inv = 1.0f / l;
    u16* cp = ctx + (((size_t)b * N_ + i) * HEADS_ + h) * HD_;
    #pragma unroll
    for (int f = 0; f < 4; ++f) {
      short8v v;
      #pragma unroll
      for (int e = 0; e < 8; ++e) v[e] = (short)f2bf(o[f*8+e] * inv);
      *(short8v*)(cp + f * 8) = v;
    }
  }
}

// ---------------- launcher ----------------
extern "C" void kernel_launch(void* const* d_in, const int* in_sizes, int n_in,
                              void* d_out, int out_size, void* d_ws, size_t ws_size,
                              hipStream_t stream) {
  const float* x      = (const float*)d_in[0];
  const float* df     = (const float*)d_in[1];
  const unsigned char* mask = (const unsigned char*)d_in[2];
  const float* qkv_w  = (const float*)d_in[3];
  const float* qkv_b  = (const float*)d_in[4];
  const float* out_w  = (const float*)d_in[5];
  const float* out_b  = (const float*)d_in[6];
  const float* dist_w = (const float*)d_in[7];
  const float* dist_b = (const float*)d_in[8];
  const float* ln1_g  = (const float*)d_in[9];
  const float* ln1_b  = (const float*)d_in[10];
  const float* ln2_g  = (const float*)d_in[11];
  const float* ln2_b  = (const float*)d_in[12];
  const float* ff1_w  = (const float*)d_in[13];
  const float* ff1_b  = (const float*)d_in[14];
  const float* ff2_w  = (const float*)d_in[15];
  const float* ff2_b  = (const float*)d_in[16];
  float* out = (float*)d_out;

  char* p = (char*)d_ws;
  auto alloc = [&](size_t bytes) {
    char* r = p;
    p += (bytes + 255) & ~(size_t)255;
    return r;
  };
  float* qkv    = (float*)alloc((size_t)ROWS * 3 * HID_ * 4);
  u16*   biasb  = (u16*)alloc((size_t)B_ * HEADS_ * N_ * N_ * 2);
  float* xa     = (float*)alloc((size_t)ROWS * HID_ * 4);
  u16*   h16    = (u16*)alloc((size_t)ROWS * HID_ * 2);
  u16*   ctx16  = (u16*)alloc((size_t)ROWS * HID_ * 2);
  u16*   y16    = (u16*)alloc((size_t)ROWS * HID_ * 2);
  u16*   ff116  = (u16*)alloc((size_t)ROWS * FFN_ * 2);
  u16*   qkv_wt = (u16*)alloc((size_t)3 * HID_ * HID_ * 2);
  u16*   out_wt = (u16*)alloc((size_t)HID_ * HID_ * 2);
  u16*   ff1_wt = (u16*)alloc((size_t)FFN_ * HID_ * 2);
  u16*   ff2_wt = (u16*)alloc((size_t)HID_ * FFN_ * 2);
  int*   flag   = (int*)alloc(sizeof(int));

  hipMemsetAsync(flag, 0, sizeof(int), stream);
  detect_mask_kernel<<<256, 256, 0, stream>>>(mask, flag);

  // weight transpose-casts (Wt[N][K] bf16)
  wt_kernel<<<dim3(3 * HID_ / 32, HID_ / 32), 256, 0, stream>>>(qkv_w, qkv_wt, HID_, 3 * HID_);
  wt_kernel<<<dim3(HID_ / 32, HID_ / 32), 256, 0, stream>>>(out_w, out_wt, HID_, HID_);
  wt_kernel<<<dim3(FFN_ / 32, HID_ / 32), 256, 0, stream>>>(ff1_w, ff1_wt, HID_, FFN_);
  wt_kernel<<<dim3(HID_ / 32, FFN_ / 32), 256, 0, stream>>>(ff2_w, ff2_wt, FFN_, HID_);

  // h16 = bf16(LN1(x))
  ln_kernel<<<ROWS / 4, 256, 0, stream>>>(x, ln1_g, ln1_b, h16);
  // qkv = h @ qkv_w + qkv_b   (f32 out)
  mfma_gemm<0, false, false><<<dim3(3 * HID_ / 128, ROWS / 128), 256, 0, stream>>>(
      h16, qkv_wt, qkv_b, nullptr, qkv, 3 * HID_, HID_);
  // biasb = bf16 masked distance bias [B,H,N,N]
  bias_kernel<<<B_ * N_ * 4, 256, 0, stream>>>(df, mask, dist_w, dist_b, flag, biasb);
  // ctx16 = bf16(softmax(QK^T/sqrt(hd) + biasb) @ V)
  attn_kernel<<<B_ * HEADS_ * 8, 256, 0, stream>>>(qkv, biasb, ctx16);
  // xa = x + ctx @ out_w + out_b   (f32 out)
  mfma_gemm<0, true, false><<<dim3(HID_ / 128, ROWS / 128), 256, 0, stream>>>(
      ctx16, out_wt, out_b, x, xa, HID_, HID_);
  // y16 = bf16(LN2(xa))
  ln_kernel<<<ROWS / 4, 256, 0, stream>>>(xa, ln2_g, ln2_b, y16);
  // ff116 = bf16(gelu(y @ ff1_w + ff1_b))
  mfma_gemm<1, false, true><<<dim3(FFN_ / 128, ROWS / 128), 256, 0, stream>>>(
      y16, ff1_wt, ff1_b, nullptr, ff116, FFN_, HID_);
  // out = xa + ff1 @ ff2_w + ff2_b   (f32 out)
  mfma_gemm<0, true, false><<<dim3(HID_ / 128, ROWS / 128), 256, 0, stream>>>(
      ff116, ff2_wt, ff2_b, xa, out, HID_, FFN_);
}

// Round 6
// 465.249 us; speedup vs baseline: 6.2431x; 1.1387x over previous
//
#include <hip/hip_runtime.h>
#include <cstddef>
#include <cstdint>

#define B_     8
#define N_     512
#define HID_   512
#define HEADS_ 16
#define HD_    32
#define FFN_   2048
#define DEMB_  64
#define ROWS   (B_*N_)   // 4096

typedef unsigned short u16;
typedef short bf16x8 __attribute__((ext_vector_type(8)));
typedef float f32x4  __attribute__((ext_vector_type(4)));
typedef short short8v __attribute__((ext_vector_type(8)));
typedef short short4v __attribute__((ext_vector_type(4)));

__device__ __forceinline__ u16 f2bf(float f) {   // RNE float->bf16
  unsigned u = __float_as_uint(f);
  u += 0x7fffu + ((u >> 16) & 1u);
  return (u16)(u >> 16);
}
__device__ __forceinline__ float bf2f(u16 b) {
  return __uint_as_float(((unsigned)b) << 16);
}

__device__ __forceinline__ void gload16(const void* g, void* l) {
  // async global->LDS, 16B/lane; LDS dest = wave-uniform base + lane*16
  __builtin_amdgcn_global_load_lds(
      (const __attribute__((address_space(1))) unsigned int*)g,
      (__attribute__((address_space(3))) unsigned int*)l, 16, 0, 0);
}

// ---------------- prep: 4x weight transpose-cast + mask dtype detect ----------------
// grid ranges: [0,768) qkv_w, [768,1024) out_w, [1024,2048) ff1_w,
// [2048,3072) ff2_w, [3072,3328) detect.
__device__ __forceinline__ void wt_tile(const float* __restrict__ W,
                                        u16* __restrict__ Wt,
                                        int K, int N, int tt, int tid) {
  __shared__ float tile[32][33];
  const int nt = N / 32;
  const int n0 = (tt % nt) * 32, k0 = (tt / nt) * 32;
  const int tx = tid & 31, ty = tid >> 5;  // ty 0..7
  #pragma unroll
  for (int i = 0; i < 4; ++i)
    tile[ty + 8 * i][tx] = W[(size_t)(k0 + ty + 8 * i) * N + n0 + tx];
  __syncthreads();
  #pragma unroll
  for (int i = 0; i < 4; ++i) {
    const int n = ty + 8 * i;
    Wt[(size_t)(n0 + n) * K + k0 + tx] = f2bf(tile[tx][n]);
  }
}

__global__ __launch_bounds__(256) void prep_kernel(
    const float* __restrict__ qkv_w, const float* __restrict__ out_w,
    const float* __restrict__ ff1_w, const float* __restrict__ ff2_w,
    u16* __restrict__ qkv_wt, u16* __restrict__ out_wt,
    u16* __restrict__ ff1_wt, u16* __restrict__ ff2_wt,
    const unsigned char* __restrict__ mask, int* __restrict__ flag) {
  const int bid = blockIdx.x, t = threadIdx.x;
  if (bid < 768) {
    wt_tile(qkv_w, qkv_wt, HID_, 3 * HID_, bid, t);
  } else if (bid < 1024) {
    wt_tile(out_w, out_wt, HID_, HID_, bid - 768, t);
  } else if (bid < 2048) {
    wt_tile(ff1_w, ff1_wt, HID_, FFN_, bid - 1024, t);
  } else if (bid < 3072) {
    wt_tile(ff2_w, ff2_wt, FFN_, HID_, bid - 2048, t);
  } else {
    // mask dtype detect: numpy bool -> random bytes everywhere;
    // int32 0/1 -> bytes at offset%4 != 0 are always 0.
    const int idx = (bid - 3072) * 256 + t;   // 0..65535
    if ((idx & 3) != 0 && mask[idx] != 0) atomicOr(flag, 1);
  }
}

// ---------------- LayerNorm (fp32 in -> bf16 out): one wave per row ----------------
__global__ __launch_bounds__(256) void ln_kernel(const float* __restrict__ x,
                                                 const float* __restrict__ g,
                                                 const float* __restrict__ bt,
                                                 u16* __restrict__ y) {
  const int lane = threadIdx.x & 63;
  const int row  = blockIdx.x * 4 + (threadIdx.x >> 6);
  const float* xr = x + (size_t)row * HID_;
  float4 v0 = *(const float4*)(xr + lane * 8);
  float4 v1 = *(const float4*)(xr + lane * 8 + 4);
  float s = v0.x + v0.y + v0.z + v0.w + v1.x + v1.y + v1.z + v1.w;
  float q = v0.x*v0.x + v0.y*v0.y + v0.z*v0.z + v0.w*v0.w
          + v1.x*v1.x + v1.y*v1.y + v1.z*v1.z + v1.w*v1.w;
  #pragma unroll
  for (int off = 32; off > 0; off >>= 1) {
    s += __shfl_xor(s, off, 64);
    q += __shfl_xor(q, off, 64);
  }
  const float mean = s * (1.0f / HID_);
  const float var  = q * (1.0f / HID_) - mean * mean;
  const float rs   = rsqrtf(var + 1e-5f);
  const float4 g0 = *(const float4*)(g + lane * 8);
  const float4 g1 = *(const float4*)(g + lane * 8 + 4);
  const float4 b0 = *(const float4*)(bt + lane * 8);
  const float4 b1 = *(const float4*)(bt + lane * 8 + 4);
  short8v o;
  o[0] = (short)f2bf((v0.x - mean) * rs * g0.x + b0.x);
  o[1] = (short)f2bf((v0.y - mean) * rs * g0.y + b0.y);
  o[2] = (short)f2bf((v0.z - mean) * rs * g0.z + b0.z);
  o[3] = (short)f2bf((v0.w - mean) * rs * g0.w + b0.w);
  o[4] = (short)f2bf((v1.x - mean) * rs * g1.x + b1.x);
  o[5] = (short)f2bf((v1.y - mean) * rs * g1.y + b1.y);
  o[6] = (short)f2bf((v1.z - mean) * rs * g1.z + b1.z);
  o[7] = (short)f2bf((v1.w - mean) * rs * g1.w + b1.w);
  *(short8v*)(y + (size_t)row * HID_ + lane * 8) = o;
}

// ---------------- bf16 MFMA GEMM: C = act(A@W + bias) (+res) ----------------
// A[M][K] bf16 row-major; Wt[N][K] bf16 (= W transposed). 128x128 tile, BK=64,
// 256 thr = 4 waves (2x2 of 64x64), mfma_f32_16x16x32_bf16, fp32 accum.
// LDS linear [row][64k]; XOR swizzle (slot ^= row&7) applied on the GLOBAL
// source during global_load_lds staging and on the ds_read address (rule #21).
// ACT: 0 none, 1 exact GELU. HAS_RES: += res. OUT_BF16: write bf16 else f32.
template <int ACT, bool HAS_RES, bool OUT_BF16>
__global__ __launch_bounds__(256) void mfma_gemm(
    const u16* __restrict__ A, const u16* __restrict__ Wt,
    const float* __restrict__ bias, const float* __restrict__ res,
    void* __restrict__ Cout, int N, int K) {
  __shared__ __align__(16) u16 As[128 * 64];
  __shared__ __align__(16) u16 Bs[128 * 64];
  const int t    = threadIdx.x;
  const int wid  = t >> 6, lane = t & 63;
  const int wr   = wid >> 1, wc = wid & 1;      // wave -> 64x64 quadrant
  const int m0   = blockIdx.y * 128, n0 = blockIdx.x * 128;
  // staging maps: each wave stages rows wid*32 .. wid*32+31 (4 insts of 8 rows)
  const int srow8 = lane >> 3;                  // 0..7 (= row&7 of the 8-row group)
  const int sslot = (lane & 7) ^ srow8;         // inverse-swizzled k-slot (involution)

  f32x4 zero = {0.f, 0.f, 0.f, 0.f};
  f32x4 acc[4][4];
  #pragma unroll
  for (int m = 0; m < 4; ++m)
    #pragma unroll
    for (int n = 0; n < 4; ++n) acc[m][n] = zero;

  for (int kt = 0; kt < K; kt += 64) {
    __syncthreads();   // previous compute done before overwriting LDS
    #pragma unroll
    for (int i = 0; i < 4; ++i) {
      const int rbase = wid * 32 + i * 8;
      const int r = rbase + srow8;
      gload16(A  + (size_t)(m0 + r) * K + kt + sslot * 8, &As[rbase * 64]);
      gload16(Wt + (size_t)(n0 + r) * K + kt + sslot * 8, &Bs[rbase * 64]);
    }
    __syncthreads();   // drains vmcnt(0) before barrier
    #pragma unroll
    for (int kk = 0; kk < 2; ++kk) {
      bf16x8 a[4], b[4];
      #pragma unroll
      for (int m = 0; m < 4; ++m) {
        const int row = wr * 64 + m * 16 + (lane & 15);
        const int s   = (kk * 4 + (lane >> 4)) ^ (row & 7);
        a[m] = *(const bf16x8*)&As[row * 64 + s * 8];
      }
      #pragma unroll
      for (int n = 0; n < 4; ++n) {
        const int row = wc * 64 + n * 16 + (lane & 15);
        const int s   = (kk * 4 + (lane >> 4)) ^ (row & 7);
        b[n] = *(const bf16x8*)&Bs[row * 64 + s * 8];
      }
      #pragma unroll
      for (int m = 0; m < 4; ++m)
        #pragma unroll
        for (int n = 0; n < 4; ++n)
          acc[m][n] = __builtin_amdgcn_mfma_f32_16x16x32_bf16(
              a[m], b[n], acc[m][n], 0, 0, 0);
    }
  }
  // epilogue: C/D layout col=lane&15, row=(lane>>4)*4+reg (m89-verified)
  #pragma unroll
  for (int n = 0; n < 4; ++n) {
    const int col = n0 + wc * 64 + n * 16 + (lane & 15);
    const float bb = bias[col];
    #pragma unroll
    for (int m = 0; m < 4; ++m) {
      #pragma unroll
      for (int j = 0; j < 4; ++j) {
        const int row = m0 + wr * 64 + m * 16 + (lane >> 4) * 4 + j;
        float v = acc[m][n][j] + bb;
        if (ACT == 1) v = 0.5f * v * (1.0f + erff(v * 0.70710678118654752f));
        const size_t off = (size_t)row * N + col;
        if (HAS_RES) v += res[off];
        if (OUT_BF16) ((u16*)Cout)[off] = f2bf(v);
        else          ((float*)Cout)[off] = v;
      }
    }
  }
}

// ---------------- fused distance-bias + mask (v3: coalesced bf16 writes) ----------------
// biasb[b,h,i,j] = bf16(mask ? df@dist_w + dist_b : -1e30)
// grid: (b, i, jtile of 128) = 16384 blocks, 256 threads = 16 h x 16 jt.
// v3: decoded mask staged once in LDS (128 loads vs 2048); outputs bounced
// through LDS so global writes are 16B short8 stores (wave = 1KB contiguous).
__global__ __launch_bounds__(256) void bias_kernel(
    const float* __restrict__ df, const unsigned char* __restrict__ mask8,
    const float* __restrict__ dw, const float* __restrict__ db,
    const int* __restrict__ flag, u16* __restrict__ biasb) {
  __shared__ float dfs[128][68];        // 34.8 KB
  __shared__ u16 obuf[HEADS_][128];     // 4 KB
  __shared__ unsigned char mbuf[128];
  const int t    = threadIdx.x;
  const int tile = blockIdx.x & 3;
  const int i    = (blockIdx.x >> 2) & 511;
  const int b    = blockIdx.x >> 11;
  const int j0   = tile * 128;
  const int h    = t >> 4;   // 0..15
  const int jt   = t & 15;   // 0..15

  // stage df[(b,i), j0..j0+127, 0..63] -> LDS, coalesced
  const float4* gsrc =
      (const float4*)(df + (((size_t)b * N_ + i) * N_ + j0) * DEMB_);
  #pragma unroll
  for (int s = 0; s < 8; ++s) {
    const int f   = s * 256 + t;       // 0..2047
    *(float4*)&dfs[f >> 4][(f & 15) * 4] = gsrc[f];
  }
  // stage decoded mask (one load per j)
  const int fb = *flag;
  if (t < 128) {
    const size_t midx = ((size_t)b * N_ + i) * N_ + j0 + t;
    mbuf[t] = fb ? (mask8[midx] != 0) : (((const int*)mask8)[midx] != 0);
  }

  // this thread's head column of dist_w (layout [d][h]) -> 16 float4 regs
  float4 w[16];
  #pragma unroll
  for (int d4 = 0; d4 < 16; ++d4) {
    w[d4].x = dw[(d4 * 4 + 0) * HEADS_ + h];
    w[d4].y = dw[(d4 * 4 + 1) * HEADS_ + h];
    w[d4].z = dw[(d4 * 4 + 2) * HEADS_ + h];
    w[d4].w = dw[(d4 * 4 + 3) * HEADS_ + h];
  }
  const float bh = db[h];
  __syncthreads();

  #pragma unroll
  for (int s = 0; s < 8; ++s) {
    const int jl = s * 16 + jt;
    float a0 = 0.f, a1 = 0.f, a2 = 0.f, a3 = 0.f;
    #pragma unroll
    for (int d4 = 0; d4 < 16; ++d4) {
      const float4 v = *(const float4*)&dfs[jl][d4 * 4];
      a0 += v.x * w[d4].x;
      a1 += v.y * w[d4].y;
      a2 += v.z * w[d4].z;
      a3 += v.w * w[d4].w;
    }
    const float acc = (a0 + a1) + (a2 + a3) + bh;
    obuf[h][jl] = f2bf(mbuf[jl] ? acc : -1e30f);
  }
  __syncthreads();
  // coalesced write-out: thread (h2,c) stores 8 consecutive j as one 16B store
  const int h2 = t >> 4, c = t & 15;
  u16* ob = biasb + (((size_t)b * HEADS_ + h2) * N_ + i) * N_ + j0;
  *(short8v*)(ob + c * 8) = *(const short8v*)&obuf[h2][c * 8];
}

// ---------------- flash attention v3 ----------------
// grid = (b, h, iblk of 64 rows) = 1024 blocks; 256 thr = 4 waves.
// Wave jq handles j in [jq*128, jq*128+128) for all 64 rows (lane = row).
// K staged bf16 in LDS (32 KB, broadcast reads); V read from global f32
// (wave-uniform address -> L1 broadcast); bias read bf16 per-lane.
// Online softmax with defer-max (THR=8); 4 partials combined via LDS union.
__global__ __launch_bounds__(256) void attn_kernel(
    const float* __restrict__ qkv, const u16* __restrict__ biasb,
    u16* __restrict__ ctx) {
  __shared__ union {
    u16 k[N_ * HD_];               // 32 KB  Ks[j][d]
    struct {
      float po[3][64][33];         // +1 pad -> conflict-free combine
      float pm[3][64];
      float pl[3][64];
    } c;
  } sm;
  const int t    = threadIdx.x;
  const int bx   = blockIdx.x;
  const int b    = bx >> 7;
  const int h    = (bx >> 3) & 15;
  const int iblk = bx & 7;
  const int jq   = t >> 6;         // wave id = j-quarter
  const int r    = t & 63;         // lane = row within block
  const int i    = iblk * 64 + r;
  const size_t qbase = (size_t)b * N_ * (3 * HID_);

  // stage K[all j][32] as bf16 (coalesced float4 reads)
  for (int idx = t; idx < N_ * 8; idx += 256) {
    const int j = idx >> 3, f = idx & 7;
    const float4 kv = *(const float4*)(qkv + qbase + (size_t)j * (3 * HID_) +
                                       HID_ + h * HD_ + f * 4);
    short4v ks;
    ks[0] = (short)f2bf(kv.x); ks[1] = (short)f2bf(kv.y);
    ks[2] = (short)f2bf(kv.z); ks[3] = (short)f2bf(kv.w);
    *(short4v*)&sm.k[j * HD_ + f * 4] = ks;
  }
  __syncthreads();

  // q regs, pre-scaled by 1/sqrt(HD)
  float q[HD_];
  {
    const float* qp = qkv + qbase + (size_t)i * (3 * HID_) + h * HD_;
    #pragma unroll
    for (int f = 0; f < 8; ++f) {
      const float4 v = *(const float4*)(qp + f * 4);
      q[f*4+0] = v.x * 0.17677669529663687f;
      q[f*4+1] = v.y * 0.17677669529663687f;
      q[f*4+2] = v.z * 0.17677669529663687f;
      q[f*4+3] = v.w * 0.17677669529663687f;
    }
  }
  const u16* brow = biasb + (((size_t)b * HEADS_ + h) * N_ + i) * N_ + jq * 128;
  const float* vbase = qkv + qbase + 2 * HID_ + h * HD_;
  float m = -3.0e38f, l = 0.f;
  float o[HD_];
  #pragma unroll
  for (int d = 0; d < HD_; ++d) o[d] = 0.f;

  for (int j8 = 0; j8 < 128; j8 += 8) {
    const short8v bq = *(const short8v*)(brow + j8);
    #pragma unroll
    for (int e = 0; e < 8; ++e) {
      const int j = jq * 128 + j8 + e;
      const u16* kr = &sm.k[j * HD_];
      float s = 0.f;
      #pragma unroll
      for (int c = 0; c < 4; ++c) {
        const short8v kk = *(const short8v*)(kr + c * 8);
        #pragma unroll
        for (int d = 0; d < 8; ++d)
          s += q[c*8+d] * bf2f((u16)kk[d]);
      }
      s += bf2f((u16)bq[e]);
      if (s - m > 8.0f) {                  // defer-max (T13)
        const float corr = __expf(m - s);
        l *= corr;
        #pragma unroll
        for (int d = 0; d < HD_; ++d) o[d] *= corr;
        m = s;
      }
      const float p = __expf(s - m);
      l += p;
      const float4* vr = (const float4*)(vbase + (size_t)j * (3 * HID_));
      #pragma unroll
      for (int c = 0; c < 8; ++c) {
        const float4 vv = vr[c];
        o[c*4+0] += p * vv.x; o[c*4+1] += p * vv.y;
        o[c*4+2] += p * vv.z; o[c*4+3] += p * vv.w;
      }
    }
  }

  __syncthreads();                  // Ks dead; LDS reused for combine
  if (jq > 0) {
    sm.c.pm[jq-1][r] = m;
    sm.c.pl[jq-1][r] = l;
    #pragma unroll
    for (int d = 0; d < HD_; ++d) sm.c.po[jq-1][r][d] = o[d];
  }
  __syncthreads();
  if (jq == 0) {
    #pragma unroll
    for (int p2 = 0; p2 < 3; ++p2) {
      const float m2 = sm.c.pm[p2][r], l2 = sm.c.pl[p2][r];
      const float mn = fmaxf(m, m2);
      const float c1 = __expf(m - mn), c2 = __expf(m2 - mn);
      l = l * c1 + l2 * c2;
      #pragma unroll
      for (int d = 0; d < HD_; ++d)
        o[d] = o[d] * c1 + sm.c.po[p2][r][d] * c2;
      m = mn;
    }
    const float inv = 1.0f / l;
    u16* cp = ctx + (((size_t)b * N_ + i) * HEADS_ + h) * HD_;
    #pragma unroll
    for (int f = 0; f < 4; ++f) {
      short8v v;
      #pragma unroll
      for (int e = 0; e < 8; ++e) v[e] = (short)f2bf(o[f*8+e] * inv);
      *(short8v*)(cp + f * 8) = v;
    }
  }
}

// ---------------- launcher ----------------
extern "C" void kernel_launch(void* const* d_in, const int* in_sizes, int n_in,
                              void* d_out, int out_size, void* d_ws, size_t ws_size,
                              hipStream_t stream) {
  const float* x      = (const float*)d_in[0];
  const float* df     = (const float*)d_in[1];
  const unsigned char* mask = (const unsigned char*)d_in[2];
  const float* qkv_w  = (const float*)d_in[3];
  const float* qkv_b  = (const float*)d_in[4];
  const float* out_w  = (const float*)d_in[5];
  const float* out_b  = (const float*)d_in[6];
  const float* dist_w = (const float*)d_in[7];
  const float* dist_b = (const float*)d_in[8];
  const float* ln1_g  = (const float*)d_in[9];
  const float* ln1_b  = (const float*)d_in[10];
  const float* ln2_g  = (const float*)d_in[11];
  const float* ln2_b  = (const float*)d_in[12];
  const float* ff1_w  = (const float*)d_in[13];
  const float* ff1_b  = (const float*)d_in[14];
  const float* ff2_w  = (const float*)d_in[15];
  const float* ff2_b  = (const float*)d_in[16];
  float* out = (float*)d_out;

  char* p = (char*)d_ws;
  auto alloc = [&](size_t bytes) {
    char* r = p;
    p += (bytes + 255) & ~(size_t)255;
    return r;
  };
  float* qkv    = (float*)alloc((size_t)ROWS * 3 * HID_ * 4);
  u16*   biasb  = (u16*)alloc((size_t)B_ * HEADS_ * N_ * N_ * 2);
  float* xa     = (float*)alloc((size_t)ROWS * HID_ * 4);
  u16*   h16    = (u16*)alloc((size_t)ROWS * HID_ * 2);
  u16*   ctx16  = (u16*)alloc((size_t)ROWS * HID_ * 2);
  u16*   y16    = (u16*)alloc((size_t)ROWS * HID_ * 2);
  u16*   ff116  = (u16*)alloc((size_t)ROWS * FFN_ * 2);
  u16*   qkv_wt = (u16*)alloc((size_t)3 * HID_ * HID_ * 2);
  u16*   out_wt = (u16*)alloc((size_t)HID_ * HID_ * 2);
  u16*   ff1_wt = (u16*)alloc((size_t)FFN_ * HID_ * 2);
  u16*   ff2_wt = (u16*)alloc((size_t)HID_ * FFN_ * 2);
  int*   flag   = (int*)alloc(sizeof(int));

  hipMemsetAsync(flag, 0, sizeof(int), stream);
  // prep: 4 weight transposes + mask detect in one launch
  prep_kernel<<<3328, 256, 0, stream>>>(qkv_w, out_w, ff1_w, ff2_w,
                                        qkv_wt, out_wt, ff1_wt, ff2_wt,
                                        mask, flag);
  // h16 = bf16(LN1(x))
  ln_kernel<<<ROWS / 4, 256, 0, stream>>>(x, ln1_g, ln1_b, h16);
  // qkv = h @ qkv_w + qkv_b   (f32 out)
  mfma_gemm<0, false, false><<<dim3(3 * HID_ / 128, ROWS / 128), 256, 0, stream>>>(
      h16, qkv_wt, qkv_b, nullptr, qkv, 3 * HID_, HID_);
  // biasb = bf16 masked distance bias [B,H,N,N]
  bias_kernel<<<B_ * N_ * 4, 256, 0, stream>>>(df, mask, dist_w, dist_b, flag, biasb);
  // ctx16 = bf16(softmax(QK^T/sqrt(hd) + biasb) @ V)
  attn_kernel<<<B_ * HEADS_ * 8, 256, 0, stream>>>(qkv, biasb, ctx16);
  // xa = x + ctx @ out_w + out_b   (f32 out)
  mfma_gemm<0, true, false><<<dim3(HID_ / 128, ROWS / 128), 256, 0, stream>>>(
      ctx16, out_wt, out_b, x, xa, HID_, HID_);
  // y16 = bf16(LN2(xa))
  ln_kernel<<<ROWS / 4, 256, 0, stream>>>(xa, ln2_g, ln2_b, y16);
  // ff116 = bf16(gelu(y @ ff1_w + ff1_b))
  mfma_gemm<1, false, true><<<dim3(FFN_ / 128, ROWS / 128), 256, 0, stream>>>(
      y16, ff1_wt, ff1_b, nullptr, ff116, FFN_, HID_);
  // out = xa + ff1 @ ff2_w + ff2_b   (f32 out)
  mfma_gemm<0, true, false><<<dim3(HID_ / 128, ROWS / 128), 256, 0, stream>>>(
      ff116, ff2_wt, ff2_b, xa, out, HID_, FFN_);
}

// Round 7
// 457.471 us; speedup vs baseline: 6.3492x; 1.0170x over previous
//
#include <hip/hip_runtime.h>
#include <cstddef>
#include <cstdint>

#define B_     8
#define N_     512
#define HID_   512
#define HEADS_ 16
#define HD_    32
#define FFN_   2048
#define DEMB_  64
#define ROWS   (B_*N_)   // 4096

typedef unsigned short u16;
typedef short bf16x8 __attribute__((ext_vector_type(8)));
typedef float f32x4  __attribute__((ext_vector_type(4)));
typedef short short8v __attribute__((ext_vector_type(8)));
typedef short short4v __attribute__((ext_vector_type(4)));

__device__ __forceinline__ u16 f2bf(float f) {   // RNE float->bf16
  unsigned u = __float_as_uint(f);
  u += 0x7fffu + ((u >> 16) & 1u);
  return (u16)(u >> 16);
}
__device__ __forceinline__ float bf2f(u16 b) {
  return __uint_as_float(((unsigned)b) << 16);
}

__device__ __forceinline__ void gload16(const void* g, void* l) {
  // async global->LDS, 16B/lane; LDS dest = wave-uniform base + lane*16
  __builtin_amdgcn_global_load_lds(
      (const __attribute__((address_space(1))) unsigned int*)g,
      (__attribute__((address_space(3))) unsigned int*)l, 16, 0, 0);
}

// ---------------- prep: 4x weight transpose-cast + mask dtype detect ----------------
__device__ __forceinline__ void wt_tile(const float* __restrict__ W,
                                        u16* __restrict__ Wt,
                                        int K, int N, int tt, int tid) {
  __shared__ float tile[32][33];
  const int nt = N / 32;
  const int n0 = (tt % nt) * 32, k0 = (tt / nt) * 32;
  const int tx = tid & 31, ty = tid >> 5;  // ty 0..7
  #pragma unroll
  for (int i = 0; i < 4; ++i)
    tile[ty + 8 * i][tx] = W[(size_t)(k0 + ty + 8 * i) * N + n0 + tx];
  __syncthreads();
  #pragma unroll
  for (int i = 0; i < 4; ++i) {
    const int n = ty + 8 * i;
    Wt[(size_t)(n0 + n) * K + k0 + tx] = f2bf(tile[tx][n]);
  }
}

__global__ __launch_bounds__(256) void prep_kernel(
    const float* __restrict__ qkv_w, const float* __restrict__ out_w,
    const float* __restrict__ ff1_w, const float* __restrict__ ff2_w,
    u16* __restrict__ qkv_wt, u16* __restrict__ out_wt,
    u16* __restrict__ ff1_wt, u16* __restrict__ ff2_wt,
    const unsigned char* __restrict__ mask, int* __restrict__ flag) {
  const int bid = blockIdx.x, t = threadIdx.x;
  if (bid < 768) {
    wt_tile(qkv_w, qkv_wt, HID_, 3 * HID_, bid, t);
  } else if (bid < 1024) {
    wt_tile(out_w, out_wt, HID_, HID_, bid - 768, t);
  } else if (bid < 2048) {
    wt_tile(ff1_w, ff1_wt, HID_, FFN_, bid - 1024, t);
  } else if (bid < 3072) {
    wt_tile(ff2_w, ff2_wt, FFN_, HID_, bid - 2048, t);
  } else {
    // mask dtype detect: numpy bool -> random bytes everywhere;
    // int32 0/1 -> bytes at offset%4 != 0 are always 0.
    const int idx = (bid - 3072) * 256 + t;   // 0..65535
    if ((idx & 3) != 0 && mask[idx] != 0) atomicOr(flag, 1);
  }
}

// ---------------- LayerNorm (fp32 in -> bf16 out): one wave per row ----------------
__global__ __launch_bounds__(256) void ln_kernel(const float* __restrict__ x,
                                                 const float* __restrict__ g,
                                                 const float* __restrict__ bt,
                                                 u16* __restrict__ y) {
  const int lane = threadIdx.x & 63;
  const int row  = blockIdx.x * 4 + (threadIdx.x >> 6);
  const float* xr = x + (size_t)row * HID_;
  float4 v0 = *(const float4*)(xr + lane * 8);
  float4 v1 = *(const float4*)(xr + lane * 8 + 4);
  float s = v0.x + v0.y + v0.z + v0.w + v1.x + v1.y + v1.z + v1.w;
  float q = v0.x*v0.x + v0.y*v0.y + v0.z*v0.z + v0.w*v0.w
          + v1.x*v1.x + v1.y*v1.y + v1.z*v1.z + v1.w*v1.w;
  #pragma unroll
  for (int off = 32; off > 0; off >>= 1) {
    s += __shfl_xor(s, off, 64);
    q += __shfl_xor(q, off, 64);
  }
  const float mean = s * (1.0f / HID_);
  const float var  = q * (1.0f / HID_) - mean * mean;
  const float rs   = rsqrtf(var + 1e-5f);
  const float4 g0 = *(const float4*)(g + lane * 8);
  const float4 g1 = *(const float4*)(g + lane * 8 + 4);
  const float4 b0 = *(const float4*)(bt + lane * 8);
  const float4 b1 = *(const float4*)(bt + lane * 8 + 4);
  short8v o;
  o[0] = (short)f2bf((v0.x - mean) * rs * g0.x + b0.x);
  o[1] = (short)f2bf((v0.y - mean) * rs * g0.y + b0.y);
  o[2] = (short)f2bf((v0.z - mean) * rs * g0.z + b0.z);
  o[3] = (short)f2bf((v0.w - mean) * rs * g0.w + b0.w);
  o[4] = (short)f2bf((v1.x - mean) * rs * g1.x + b1.x);
  o[5] = (short)f2bf((v1.y - mean) * rs * g1.y + b1.y);
  o[6] = (short)f2bf((v1.z - mean) * rs * g1.z + b1.z);
  o[7] = (short)f2bf((v1.w - mean) * rs * g1.w + b1.w);
  *(short8v*)(y + (size_t)row * HID_ + lane * 8) = o;
}

// ---------------- bf16 MFMA GEMM (v2: double-buffered 2-phase prefetch) ----
// A[M][K] bf16 row-major; Wt[N][K] bf16. 128x128 tile, BK=64, 4 waves,
// mfma_f32_16x16x32_bf16, fp32 accum. T3-minimum schedule: stage(buf^1,t+1)
// issued BEFORE compute(buf,t); one __syncthreads (vmcnt0 drain) per K-step.
// XOR swizzle (slot ^= row&7) on global source + ds_read (rule #21).
template <int ACT, bool HAS_RES, bool OUT_BF16>
__global__ __launch_bounds__(256) void mfma_gemm(
    const u16* __restrict__ A, const u16* __restrict__ Wt,
    const float* __restrict__ bias, const float* __restrict__ res,
    void* __restrict__ Cout, int N, int K) {
  __shared__ __align__(16) u16 As[2][128 * 64];
  __shared__ __align__(16) u16 Bs[2][128 * 64];
  const int t    = threadIdx.x;
  const int wid  = t >> 6, lane = t & 63;
  const int wr   = wid >> 1, wc = wid & 1;      // wave -> 64x64 quadrant
  const int m0   = blockIdx.y * 128, n0 = blockIdx.x * 128;
  const int srow8 = lane >> 3;                  // 0..7
  const int sslot = (lane & 7) ^ srow8;         // inverse-swizzled k-slot

  f32x4 zero = {0.f, 0.f, 0.f, 0.f};
  f32x4 acc[4][4];
  #pragma unroll
  for (int m = 0; m < 4; ++m)
    #pragma unroll
    for (int n = 0; n < 4; ++n) acc[m][n] = zero;

  auto stage = [&](int buf, int kt) {
    #pragma unroll
    for (int i = 0; i < 4; ++i) {
      const int rbase = wid * 32 + i * 8;
      const int r = rbase + srow8;
      gload16(A  + (size_t)(m0 + r) * K + kt + sslot * 8, &As[buf][rbase * 64]);
      gload16(Wt + (size_t)(n0 + r) * K + kt + sslot * 8, &Bs[buf][rbase * 64]);
    }
  };

  const int nsteps = K >> 6;
  stage(0, 0);
  __syncthreads();                 // drain prologue loads
  int cur = 0;
  for (int step = 0; step < nsteps; ++step) {
    if (step + 1 < nsteps) stage(cur ^ 1, (step + 1) * 64);  // prefetch
    #pragma unroll
    for (int kk = 0; kk < 2; ++kk) {
      bf16x8 a[4], b[4];
      #pragma unroll
      for (int m = 0; m < 4; ++m) {
        const int row = wr * 64 + m * 16 + (lane & 15);
        const int s   = (kk * 4 + (lane >> 4)) ^ (row & 7);
        a[m] = *(const bf16x8*)&As[cur][row * 64 + s * 8];
      }
      #pragma unroll
      for (int n = 0; n < 4; ++n) {
        const int row = wc * 64 + n * 16 + (lane & 15);
        const int s   = (kk * 4 + (lane >> 4)) ^ (row & 7);
        b[n] = *(const bf16x8*)&Bs[cur][row * 64 + s * 8];
      }
      #pragma unroll
      for (int m = 0; m < 4; ++m)
        #pragma unroll
        for (int n = 0; n < 4; ++n)
          acc[m][n] = __builtin_amdgcn_mfma_f32_16x16x32_bf16(
              a[m], b[n], acc[m][n], 0, 0, 0);
    }
    __syncthreads();               // drains vmcnt(0)+lgkmcnt(0) for all waves
    cur ^= 1;
  }
  // epilogue: C/D layout col=lane&15, row=(lane>>4)*4+reg (m89-verified)
  #pragma unroll
  for (int n = 0; n < 4; ++n) {
    const int col = n0 + wc * 64 + n * 16 + (lane & 15);
    const float bb = bias[col];
    #pragma unroll
    for (int m = 0; m < 4; ++m) {
      #pragma unroll
      for (int j = 0; j < 4; ++j) {
        const int row = m0 + wr * 64 + m * 16 + (lane >> 4) * 4 + j;
        float v = acc[m][n][j] + bb;
        if (ACT == 1) v = 0.5f * v * (1.0f + erff(v * 0.70710678118654752f));
        const size_t off = (size_t)row * N + col;
        if (HAS_RES) v += res[off];
        if (OUT_BF16) ((u16*)Cout)[off] = f2bf(v);
        else          ((float*)Cout)[off] = v;
      }
    }
  }
}

// ---------------- fused distance-bias + mask (v4: MFMA) ----------------
// bias[b,h,i,j] = bf16(mask ? df[b,i,j,:]@dist_w[:,h] + dist_b[h] : -1e30)
// = [128 rows (j)] x [K=64 (d)] x [16 cols (h)] matmul per block -> MFMA.
// df staged f32 via gload16 with 16B-group XOR swizzle g = p ^ (row&15)
// (rule #21: inverse-swz source + swz read). Frags built bf16 in-register.
// Output bounced through padded LDS -> 16B coalesced stores.
__global__ __launch_bounds__(256) void bias_kernel(
    const float* __restrict__ df, const unsigned char* __restrict__ mask8,
    const float* __restrict__ dw, const float* __restrict__ db,
    const int* __restrict__ flag, u16* __restrict__ biasb) {
  __shared__ __align__(16) float dfs[128 * 64];   // 32 KB, group-swizzled
  __shared__ float wls[64 * 16];                  // 4 KB, [d][h] linear
  __shared__ float dbs[16];
  __shared__ unsigned char mbuf[128];
  __shared__ u16 obuf[16][132];                   // pad 132 -> conflict-free

  const int t    = threadIdx.x;
  const int wid  = t >> 6, lane = t & 63;
  const int tile = blockIdx.x & 3;
  const int i    = (blockIdx.x >> 2) & 511;
  const int b    = blockIdx.x >> 11;
  const int j0   = tile * 128;

  // stage df[128 rows][64 f32]: physical 16B-slot p of row r holds group p^(r&15)
  const size_t dfbase = (((size_t)b * N_ + i) * N_ + j0) * DEMB_;
  #pragma unroll
  for (int s = 0; s < 8; ++s) {
    const int r0 = wid * 32 + s * 4;
    const int r  = r0 + (lane >> 4);
    const int g  = (lane & 15) ^ (r & 15);
    gload16(df + dfbase + (size_t)r * DEMB_ + g * 4, &dfs[r0 * 64]);
  }
  // stage dist_w (f32 [64][16], 4KB, linear) + db + decoded mask
  *(float4*)&wls[t * 4] = ((const float4*)dw)[t];
  if (t < 16) dbs[t] = db[t];
  const int fb = *flag;
  if (t < 128) {
    const size_t midx = ((size_t)b * N_ + i) * N_ + j0 + t;
    mbuf[t] = fb ? (mask8[midx] != 0) : (((const int*)mask8)[midx] != 0);
  }
  __syncthreads();

  // B frags: lane holds col h=lane&15, k = kk*32 + (lane>>4)*8 + e
  bf16x8 bw[2];
  #pragma unroll
  for (int kk = 0; kk < 2; ++kk)
    #pragma unroll
    for (int e = 0; e < 8; ++e) {
      const int k = kk * 32 + (lane >> 4) * 8 + e;
      bw[kk][e] = (short)f2bf(wls[k * 16 + (lane & 15)]);
    }

  // A frags + MFMA: wave -> rows [wid*32, wid*32+32) as 2 tiles of 16
  f32x4 acc[2] = {{0.f,0.f,0.f,0.f},{0.f,0.f,0.f,0.f}};
  #pragma unroll
  for (int t8 = 0; t8 < 2; ++t8) {
    const int row = wid * 32 + t8 * 16 + (lane & 15);
    #pragma unroll
    for (int kk = 0; kk < 2; ++kk) {
      bf16x8 a;
      #pragma unroll
      for (int gg = 0; gg < 2; ++gg) {
        const int G = kk * 8 + (lane >> 4) * 2 + gg;
        const int p = G ^ (row & 15);
        const float4 v = *(const float4*)&dfs[row * 64 + p * 4];
        a[gg*4+0] = (short)f2bf(v.x); a[gg*4+1] = (short)f2bf(v.y);
        a[gg*4+2] = (short)f2bf(v.z); a[gg*4+3] = (short)f2bf(v.w);
      }
      acc[t8] = __builtin_amdgcn_mfma_f32_16x16x32_bf16(a, bw[kk], acc[t8], 0, 0, 0);
    }
  }

  // epilogue: C col=lane&15 (h), row=(lane>>4)*4+j -> obuf, then coalesced out
  const int h = lane & 15;
  #pragma unroll
  for (int t8 = 0; t8 < 2; ++t8)
    #pragma unroll
    for (int j = 0; j < 4; ++j) {
      const int jl = wid * 32 + t8 * 16 + (lane >> 4) * 4 + j;
      const float v = acc[t8][j] + dbs[h];
      obuf[h][jl] = f2bf(mbuf[jl] ? v : -1e30f);
    }
  __syncthreads();
  const int h2 = t >> 4, c = t & 15;
  u16* ob = biasb + (((size_t)b * HEADS_ + h2) * N_ + i) * N_ + j0;
  *(short8v*)(ob + c * 8) = *(const short8v*)&obuf[h2][c * 8];
}

// ---------------- flash attention v3 ----------------
// grid = (b, h, iblk of 64 rows) = 1024 blocks; 256 thr = 4 waves.
// Wave jq handles j in [jq*128, jq*128+128) for all 64 rows (lane = row).
__global__ __launch_bounds__(256) void attn_kernel(
    const float* __restrict__ qkv, const u16* __restrict__ biasb,
    u16* __restrict__ ctx) {
  __shared__ union {
    u16 k[N_ * HD_];               // 32 KB  Ks[j][d]
    struct {
      float po[3][64][33];         // +1 pad -> conflict-free combine
      float pm[3][64];
      float pl[3][64];
    } c;
  } sm;
  const int t    = threadIdx.x;
  const int bx   = blockIdx.x;
  const int b    = bx >> 7;
  const int h    = (bx >> 3) & 15;
  const int iblk = bx & 7;
  const int jq   = t >> 6;         // wave id = j-quarter
  const int r    = t & 63;         // lane = row within block
  const int i    = iblk * 64 + r;
  const size_t qbase = (size_t)b * N_ * (3 * HID_);

  for (int idx = t; idx < N_ * 8; idx += 256) {
    const int j = idx >> 3, f = idx & 7;
    const float4 kv = *(const float4*)(qkv + qbase + (size_t)j * (3 * HID_) +
                                       HID_ + h * HD_ + f * 4);
    short4v ks;
    ks[0] = (short)f2bf(kv.x); ks[1] = (short)f2bf(kv.y);
    ks[2] = (short)f2bf(kv.z); ks[3] = (short)f2bf(kv.w);
    *(short4v*)&sm.k[j * HD_ + f * 4] = ks;
  }
  __syncthreads();

  float q[HD_];
  {
    const float* qp = qkv + qbase + (size_t)i * (3 * HID_) + h * HD_;
    #pragma unroll
    for (int f = 0; f < 8; ++f) {
      const float4 v = *(const float4*)(qp + f * 4);
      q[f*4+0] = v.x * 0.17677669529663687f;
      q[f*4+1] = v.y * 0.17677669529663687f;
      q[f*4+2] = v.z * 0.17677669529663687f;
      q[f*4+3] = v.w * 0.17677669529663687f;
    }
  }
  const u16* brow = biasb + (((size_t)b * HEADS_ + h) * N_ + i) * N_ + jq * 128;
  const float* vbase = qkv + qbase + 2 * HID_ + h * HD_;
  float m = -3.0e38f, l = 0.f;
  float o[HD_];
  #pragma unroll
  for (int d = 0; d < HD_; ++d) o[d] = 0.f;

  for (int j8 = 0; j8 < 128; j8 += 8) {
    const short8v bq = *(const short8v*)(brow + j8);
    #pragma unroll
    for (int e = 0; e < 8; ++e) {
      const int j = jq * 128 + j8 + e;
      const u16* kr = &sm.k[j * HD_];
      float s = 0.f;
      #pragma unroll
      for (int c = 0; c < 4; ++c) {
        const short8v kk = *(const short8v*)(kr + c * 8);
        #pragma unroll
        for (int d = 0; d < 8; ++d)
          s += q[c*8+d] * bf2f((u16)kk[d]);
      }
      s += bf2f((u16)bq[e]);
      if (s - m > 8.0f) {                  // defer-max (T13)
        const float corr = __expf(m - s);
        l *= corr;
        #pragma unroll
        for (int d = 0; d < HD_; ++d) o[d] *= corr;
        m = s;
      }
      const float p = __expf(s - m);
      l += p;
      const float4* vr = (const float4*)(vbase + (size_t)j * (3 * HID_));
      #pragma unroll
      for (int c = 0; c < 8; ++c) {
        const float4 vv = vr[c];
        o[c*4+0] += p * vv.x; o[c*4+1] += p * vv.y;
        o[c*4+2] += p * vv.z; o[c*4+3] += p * vv.w;
      }
    }
  }

  __syncthreads();                  // Ks dead; LDS reused for combine
  if (jq > 0) {
    sm.c.pm[jq-1][r] = m;
    sm.c.pl[jq-1][r] = l;
    #pragma unroll
    for (int d = 0; d < HD_; ++d) sm.c.po[jq-1][r][d] = o[d];
  }
  __syncthreads();
  if (jq == 0) {
    #pragma unroll
    for (int p2 = 0; p2 < 3; ++p2) {
      const float m2 = sm.c.pm[p2][r], l2 = sm.c.pl[p2][r];
      const float mn = fmaxf(m, m2);
      const float c1 = __expf(m - mn), c2 = __expf(m2 - mn);
      l = l * c1 + l2 * c2;
      #pragma unroll
      for (int d = 0; d < HD_; ++d)
        o[d] = o[d] * c1 + sm.c.po[p2][r][d] * c2;
      m = mn;
    }
    const float inv = 1.0f / l;
    u16* cp = ctx + (((size_t)b * N_ + i) * HEADS_ + h) * HD_;
    #pragma unroll
    for (int f = 0; f < 4; ++f) {
      short8v v;
      #pragma unroll
      for (int e = 0; e < 8; ++e) v[e] = (short)f2bf(o[f*8+e] * inv);
      *(short8v*)(cp + f * 8) = v;
    }
  }
}

// ---------------- launcher ----------------
extern "C" void kernel_launch(void* const* d_in, const int* in_sizes, int n_in,
                              void* d_out, int out_size, void* d_ws, size_t ws_size,
                              hipStream_t stream) {
  const float* x      = (const float*)d_in[0];
  const float* df     = (const float*)d_in[1];
  const unsigned char* mask = (const unsigned char*)d_in[2];
  const float* qkv_w  = (const float*)d_in[3];
  const float* qkv_b  = (const float*)d_in[4];
  const float* out_w  = (const float*)d_in[5];
  const float* out_b  = (const float*)d_in[6];
  const float* dist_w = (const float*)d_in[7];
  const float* dist_b = (const float*)d_in[8];
  const float* ln1_g  = (const float*)d_in[9];
  const float* ln1_b  = (const float*)d_in[10];
  const float* ln2_g  = (const float*)d_in[11];
  const float* ln2_b  = (const float*)d_in[12];
  const float* ff1_w  = (const float*)d_in[13];
  const float* ff1_b  = (const float*)d_in[14];
  const float* ff2_w  = (const float*)d_in[15];
  const float* ff2_b  = (const float*)d_in[16];
  float* out = (float*)d_out;

  char* p = (char*)d_ws;
  auto alloc = [&](size_t bytes) {
    char* r = p;
    p += (bytes + 255) & ~(size_t)255;
    return r;
  };
  float* qkv    = (float*)alloc((size_t)ROWS * 3 * HID_ * 4);
  u16*   biasb  = (u16*)alloc((size_t)B_ * HEADS_ * N_ * N_ * 2);
  float* xa     = (float*)alloc((size_t)ROWS * HID_ * 4);
  u16*   h16    = (u16*)alloc((size_t)ROWS * HID_ * 2);
  u16*   ctx16  = (u16*)alloc((size_t)ROWS * HID_ * 2);
  u16*   y16    = (u16*)alloc((size_t)ROWS * HID_ * 2);
  u16*   ff116  = (u16*)alloc((size_t)ROWS * FFN_ * 2);
  u16*   qkv_wt = (u16*)alloc((size_t)3 * HID_ * HID_ * 2);
  u16*   out_wt = (u16*)alloc((size_t)HID_ * HID_ * 2);
  u16*   ff1_wt = (u16*)alloc((size_t)FFN_ * HID_ * 2);
  u16*   ff2_wt = (u16*)alloc((size_t)HID_ * FFN_ * 2);
  int*   flag   = (int*)alloc(sizeof(int));

  hipMemsetAsync(flag, 0, sizeof(int), stream);
  prep_kernel<<<3328, 256, 0, stream>>>(qkv_w, out_w, ff1_w, ff2_w,
                                        qkv_wt, out_wt, ff1_wt, ff2_wt,
                                        mask, flag);
  // h16 = bf16(LN1(x))
  ln_kernel<<<ROWS / 4, 256, 0, stream>>>(x, ln1_g, ln1_b, h16);
  // qkv = h @ qkv_w + qkv_b   (f32 out)
  mfma_gemm<0, false, false><<<dim3(3 * HID_ / 128, ROWS / 128), 256, 0, stream>>>(
      h16, qkv_wt, qkv_b, nullptr, qkv, 3 * HID_, HID_);
  // biasb = bf16 masked distance bias [B,H,N,N]  (MFMA)
  bias_kernel<<<B_ * N_ * 4, 256, 0, stream>>>(df, mask, dist_w, dist_b, flag, biasb);
  // ctx16 = bf16(softmax(QK^T/sqrt(hd) + biasb) @ V)
  attn_kernel<<<B_ * HEADS_ * 8, 256, 0, stream>>>(qkv, biasb, ctx16);
  // xa = x + ctx @ out_w + out_b   (f32 out)
  mfma_gemm<0, true, false><<<dim3(HID_ / 128, ROWS / 128), 256, 0, stream>>>(
      ctx16, out_wt, out_b, x, xa, HID_, HID_);
  // y16 = bf16(LN2(xa))
  ln_kernel<<<ROWS / 4, 256, 0, stream>>>(xa, ln2_g, ln2_b, y16);
  // ff116 = bf16(gelu(y @ ff1_w + ff1_b))
  mfma_gemm<1, false, true><<<dim3(FFN_ / 128, ROWS / 128), 256, 0, stream>>>(
      y16, ff1_wt, ff1_b, nullptr, ff116, FFN_, HID_);
  // out = xa + ff1 @ ff2_w + ff2_b   (f32 out)
  mfma_gemm<0, true, false><<<dim3(HID_ / 128, ROWS / 128), 256, 0, stream>>>(
      ff116, ff2_wt, ff2_b, xa, out, HID_, FFN_);
}